// Round 12
// baseline (909.439 us; speedup 1.0000x reference)
//
#include <hip/hip_runtime.h>

#define D 64
#define RPB 128          // output rows per bucket (LDS tile)
#define NB_MAX 1024      // max buckets per side  -> nEnt,nU <= 131072
#define CHUNK 4096       // items per partition block
#define IPT 16           // items per thread (256*16 = 4096)

// ===========================================================================
// disen_weight = softmax(disen_weight_att, axis=-1) @ relation_emb   [F, D]
// ===========================================================================
__global__ void disen_kernel(const float* __restrict__ att, const float* __restrict__ rel,
                             float* __restrict__ disen, int nF, int nRel) {
    int d = threadIdx.x;
    if (d >= D) return;
    for (int f = 0; f < nF; ++f) {
        float m = -1e30f;
        for (int r = 0; r < nRel; ++r) m = fmaxf(m, att[f * nRel + r]);
        float sum = 0.0f, w = 0.0f;
        for (int r = 0; r < nRel; ++r) {
            float ex = __expf(att[f * nRel + r] - m);
            sum += ex;
            w   += ex * rel[r * D + d];
        }
        disen[f * D + d] = w / sum;
    }
}

// ===========================================================================
// entity_emb f32 -> bf16 (RNE): halves random-gather bytes in agg.
// ===========================================================================
__global__ void ent_to_bf16(const float* __restrict__ ent,
                            unsigned short* __restrict__ entb, int total) {
    int i = blockIdx.x * blockDim.x + threadIdx.x;
    if (i >= total) return;
    unsigned int u = __float_as_uint(ent[i]);
    u = u + 0x7FFFu + ((u >> 16) & 1u);
    entb[i] = (unsigned short)(u >> 16);
}

__device__ __forceinline__ float bf16_to_f32(unsigned short h) {
    return __uint_as_float(((unsigned int)h) << 16);
}

// ===========================================================================
// Partition (entities): bucket = head >> 7. LDS hist -> block scan ->
// one global atomic per (block,bucket) -> LDS reorder -> coalesced-run write.
// Payload int: tail(20) | type(5)<<20 | row_local(7)<<25.
// Overflow (cap exceeded; ~impossible for uniform data): direct f32 atomics
// into pre-zeroed eagg + ovcnt.
// ===========================================================================
__global__ void part_e(const int* __restrict__ eidx, const int* __restrict__ etype,
                       int nE, int* __restrict__ g_cnt, int* __restrict__ region,
                       int cap, const float* __restrict__ ent,
                       const float* __restrict__ rel, float* __restrict__ eagg,
                       int* __restrict__ ovcnt) {
    __shared__ int hist[NB_MAX], sA[NB_MAX], sB[NB_MAX], gbase[NB_MAX], lcur[NB_MAX];
    __shared__ int litems[CHUNK];
    __shared__ unsigned short lbkt[CHUNK];
    int tid = threadIdx.x;
    int c0 = blockIdx.x * CHUNK;
    int c1 = min(c0 + CHUNK, nE);

    for (int b = tid; b < NB_MAX; b += 256) hist[b] = 0;
    __syncthreads();
    for (int j = 0; j < IPT; ++j) {
        int i = c0 + j * 256 + tid;
        if (i < c1) atomicAdd(&hist[eidx[i] >> 7], 1);
    }
    __syncthreads();
    // inclusive scan (Hillis-Steele, fixed 10 iters for NB_MAX=1024) -> sA
    for (int b = tid; b < NB_MAX; b += 256) sA[b] = hist[b];
    __syncthreads();
    bool flip = false;
    for (int off = 1; off < NB_MAX; off <<= 1) {
        int* src = flip ? sB : sA;
        int* dst = flip ? sA : sB;
        for (int b = tid; b < NB_MAX; b += 256)
            dst[b] = src[b] + ((b >= off) ? src[b - off] : 0);
        __syncthreads();
        flip = !flip;
    }  // 10 iterations (even) -> final inclusive scan in sA
    for (int b = tid; b < NB_MAX; b += 256) {
        int h = hist[b];
        sB[b] = sA[b] - h;                                   // exclusive base (local)
        lcur[b] = 0;
        gbase[b] = h ? atomicAdd(&g_cnt[b], h) : 0;          // global reservation
    }
    __syncthreads();
    for (int j = 0; j < IPT; ++j) {
        int i = c0 + j * 256 + tid;
        if (i < c1) {
            int h = eidx[i];
            int b = h >> 7;
            unsigned rl = (unsigned)(h & 127);
            unsigned tail = (unsigned)eidx[nE + i];
            unsigned ty = (unsigned)etype[i];
            int payload = (int)(tail | (ty << 20) | (rl << 25));
            int rank = atomicAdd(&lcur[b], 1);
            int lpos = sB[b] + rank;
            litems[lpos] = payload;
            lbkt[lpos] = (unsigned short)b;
        }
    }
    __syncthreads();
    int cnt_chunk = c1 - c0;
    for (int j = tid; j < cnt_chunk; j += 256) {
        int b = lbkt[j];
        int payload = litems[j];
        int gpos = gbase[b] + (j - sB[b]);
        if (gpos < cap) {
            region[(size_t)b * cap + gpos] = payload;        // coalesced runs
        } else {                                             // rare overflow
            unsigned p = (unsigned)payload;
            int tail = (int)(p & 0xFFFFF);
            int ty = (int)((p >> 20) & 31);
            int rl = (int)((p >> 25) & 127);
            int row = b * RPB + rl;
            for (int d = 0; d < D; ++d)
                atomicAdd(&eagg[(size_t)row * D + d],
                          ent[(size_t)tail * D + d] * rel[ty * D + d]);
            atomicAdd(&ovcnt[row], 1);
        }
    }
}

// ===========================================================================
// Partition (users): bucket = row >> 7. Payload int2{col | rl<<20, val_bits}.
// ===========================================================================
__global__ void part_u(const int* __restrict__ irows, const int* __restrict__ icols,
                       const float* __restrict__ vals, int nnz,
                       int* __restrict__ g_cnt, int2* __restrict__ region, int cap,
                       const float* __restrict__ ent, float* __restrict__ uagg) {
    __shared__ int hist[NB_MAX], sA[NB_MAX], sB[NB_MAX], gbase[NB_MAX], lcur[NB_MAX];
    __shared__ int2 litems[CHUNK];
    __shared__ unsigned short lbkt[CHUNK];
    int tid = threadIdx.x;
    int c0 = blockIdx.x * CHUNK;
    int c1 = min(c0 + CHUNK, nnz);

    for (int b = tid; b < NB_MAX; b += 256) hist[b] = 0;
    __syncthreads();
    for (int j = 0; j < IPT; ++j) {
        int i = c0 + j * 256 + tid;
        if (i < c1) atomicAdd(&hist[irows[i] >> 7], 1);
    }
    __syncthreads();
    for (int b = tid; b < NB_MAX; b += 256) sA[b] = hist[b];
    __syncthreads();
    bool flip = false;
    for (int off = 1; off < NB_MAX; off <<= 1) {
        int* src = flip ? sB : sA;
        int* dst = flip ? sA : sB;
        for (int b = tid; b < NB_MAX; b += 256)
            dst[b] = src[b] + ((b >= off) ? src[b - off] : 0);
        __syncthreads();
        flip = !flip;
    }
    for (int b = tid; b < NB_MAX; b += 256) {
        int h = hist[b];
        sB[b] = sA[b] - h;
        lcur[b] = 0;
        gbase[b] = h ? atomicAdd(&g_cnt[b], h) : 0;
    }
    __syncthreads();
    for (int j = 0; j < IPT; ++j) {
        int i = c0 + j * 256 + tid;
        if (i < c1) {
            int r = irows[i];
            int b = r >> 7;
            unsigned rl = (unsigned)(r & 127);
            int2 payload = make_int2((int)((unsigned)icols[i] | (rl << 20)),
                                     __float_as_int(vals[i]));
            int rank = atomicAdd(&lcur[b], 1);
            int lpos = sB[b] + rank;
            litems[lpos] = payload;
            lbkt[lpos] = (unsigned short)b;
        }
    }
    __syncthreads();
    int cnt_chunk = c1 - c0;
    for (int j = tid; j < cnt_chunk; j += 256) {
        int b = lbkt[j];
        int2 payload = litems[j];
        int gpos = gbase[b] + (j - sB[b]);
        if (gpos < cap) {
            region[(size_t)b * cap + gpos] = payload;
        } else {                                             // rare overflow
            int col = payload.x & 0xFFFFF;
            int rl = (int)(((unsigned)payload.x >> 20) & 127);
            float v = __int_as_float(payload.y);
            int row = b * RPB + rl;
            for (int d = 0; d < D; ++d)
                atomicAdd(&uagg[(size_t)row * D + d],
                          ent[(size_t)col * D + d] * v);
        }
    }
}

// ===========================================================================
// Fused aggregation: block per bucket (users first, then entities).
// 128 output rows live in LDS; items stream sequentially; only the entb
// gathers are random (128B line-aligned, 8 in flight per wave).
// ===========================================================================
__global__ void agg_bkt(const unsigned short* __restrict__ entb,
                        const float* __restrict__ rel,
                        const int* __restrict__ region_e, const int* __restrict__ cnt_e,
                        int cap_e, const int* __restrict__ ovcnt_e,
                        const int2* __restrict__ region_u, const int* __restrict__ cnt_u,
                        int cap_u,
                        const float* __restrict__ uemb, const float* __restrict__ lat,
                        const float* __restrict__ disen,
                        float* __restrict__ eagg, float* __restrict__ uagg,
                        int nEnt, int nU, int nbu) {
    __shared__ float acc[RPB * D];     // 32 KB
    __shared__ int rcnt[RPB];
    int tid = threadIdx.x;
    int wid = tid >> 6;
    int d = tid & 63;
    for (int idx = tid; idx < RPB * D; idx += 256) acc[idx] = 0.0f;
    for (int r = tid; r < RPB; r += 256) rcnt[r] = 0;
    __syncthreads();

    int b = blockIdx.x;
    if (b < nbu) {
        // ---------------- user bucket ----------------
        int n = min(cnt_u[b], cap_u);
        const int2* reg = region_u + (size_t)b * cap_u;
        for (int base_i = wid * 8; base_i < n; base_i += 32) {
            int m = min(8, n - base_i);
            float v[8];
            int rl[8];
#pragma unroll
            for (int k = 0; k < 8; ++k) {
                if (k < m) {
                    int2 p = reg[base_i + k];
                    int col = p.x & 0xFFFFF;
                    rl[k] = (int)(((unsigned)p.x >> 20) & 127);
                    v[k] = bf16_to_f32(entb[(size_t)col * D + d]) *
                           __int_as_float(p.y);
                }
            }
#pragma unroll
            for (int k = 0; k < 8; ++k)
                if (k < m) atomicAdd(&acc[rl[k] * D + d], v[k]);
        }
        __syncthreads();
        // epilogue: wave handles 32 rows
        for (int r = wid * 32; r < wid * 32 + 32; ++r) {
            int R = b * RPB + r;
            if (R >= nU) continue;
            float aggv = acc[r * D + d] + uagg[(size_t)R * D + d];  // + overflow base
            float e = uemb[(size_t)R * D + d];
            float s[4];
#pragma unroll
            for (int f = 0; f < 4; ++f) {
                float p = e * lat[f * D + d];
#pragma unroll
                for (int off = 32; off > 0; off >>= 1) p += __shfl_xor(p, off, 64);
                s[f] = p;
            }
            float mx = fmaxf(fmaxf(s[0], s[1]), fmaxf(s[2], s[3]));
            float sum = 0.0f;
#pragma unroll
            for (int f = 0; f < 4; ++f) { s[f] = __expf(s[f] - mx); sum += s[f]; }
            float inv = 1.0f / sum;
            float watt = 0.0f;
#pragma unroll
            for (int f = 0; f < 4; ++f) watt += (s[f] * inv) * disen[f * D + d];
            uagg[(size_t)R * D + d] = watt * aggv + aggv;
        }
        return;
    }

    // ---------------- entity bucket ----------------
    int be = b - nbu;
    int n = min(cnt_e[be], cap_e);
    const int* reg = region_e + (size_t)be * cap_e;
    for (int base_i = wid * 8; base_i < n; base_i += 32) {
        int m = min(8, n - base_i);
        float v[8];
        int rl[8];
#pragma unroll
        for (int k = 0; k < 8; ++k) {
            if (k < m) {
                unsigned p = (unsigned)reg[base_i + k];
                int tail = (int)(p & 0xFFFFF);
                int ty = (int)((p >> 20) & 31);
                rl[k] = (int)((p >> 25) & 127);
                v[k] = bf16_to_f32(entb[(size_t)tail * D + d]) * rel[ty * D + d];
            }
        }
#pragma unroll
        for (int k = 0; k < 8; ++k) {
            if (k < m) {
                atomicAdd(&acc[rl[k] * D + d], v[k]);
                if (d == 0) atomicAdd(&rcnt[rl[k]], 1);
            }
        }
    }
    __syncthreads();
    for (int idx = tid; idx < RPB * D; idx += 256) {
        int r = idx >> 6, dd = idx & 63;
        int R = be * RPB + r;
        if (R < nEnt) {
            float c = (float)(rcnt[r] + ovcnt_e[R]);
            size_t o = (size_t)R * D + dd;
            eagg[o] = (acc[idx] + eagg[o]) / fmaxf(c, 1.0f);  // + overflow base
        }
    }
}

// ===========================================================================
// FALLBACK: direct atomic scatter (round-3 proven path)
// ===========================================================================
__global__ void kg_scatter(const float* __restrict__ ent, const float* __restrict__ rel,
                           const int* __restrict__ eidx, const int* __restrict__ etype,
                           float* __restrict__ eagg, float* __restrict__ cnt, int nE) {
    int gid = blockIdx.x * blockDim.x + threadIdx.x;
    int e = gid >> 6;
    if (e >= nE) return;
    int d = gid & 63;
    int head = eidx[e];
    int tail = eidx[nE + e];
    int t = etype[e];
    float v = ent[tail * D + d] * rel[t * D + d];
    atomicAdd(&eagg[(size_t)head * D + d], v);
    if (d == 0) atomicAdd(&cnt[head], 1.0f);
}

__global__ void spmm_scatter(const float* __restrict__ ent, const float* __restrict__ vals,
                             const int* __restrict__ rows, const int* __restrict__ cols,
                             float* __restrict__ uagg, int nnz) {
    int gid = blockIdx.x * blockDim.x + threadIdx.x;
    int i = gid >> 6;
    if (i >= nnz) return;
    int d = gid & 63;
    float v = ent[cols[i] * D + d] * vals[i];
    atomicAdd(&uagg[(size_t)rows[i] * D + d], v);
}

__global__ void ent_norm(float* __restrict__ eagg, const float* __restrict__ cnt,
                         int total) {
    int gid = blockIdx.x * blockDim.x + threadIdx.x;
    if (gid >= total) return;
    float c = cnt[gid >> 6];
    eagg[gid] /= fmaxf(c, 1.0f);
}

__global__ void user_final(const float* __restrict__ uemb, const float* __restrict__ lat,
                           const float* __restrict__ disen, float* __restrict__ uagg,
                           int nU) {
    int gid = blockIdx.x * blockDim.x + threadIdx.x;
    int u = gid >> 6;
    if (u >= nU) return;
    int d = gid & 63;
    float e = uemb[(size_t)u * D + d];
    float s[4];
#pragma unroll
    for (int f = 0; f < 4; ++f) {
        float p = e * lat[f * D + d];
#pragma unroll
        for (int off = 32; off > 0; off >>= 1) p += __shfl_xor(p, off, 64);
        s[f] = p;
    }
    float m = fmaxf(fmaxf(s[0], s[1]), fmaxf(s[2], s[3]));
    float sum = 0.0f;
#pragma unroll
    for (int f = 0; f < 4; ++f) { s[f] = __expf(s[f] - m); sum += s[f]; }
    float inv = 1.0f / sum;
    float w = 0.0f;
#pragma unroll
    for (int f = 0; f < 4; ++f) w += (s[f] * inv) * disen[f * D + d];
    size_t o = (size_t)u * D + d;
    float base = uagg[o];
    uagg[o] = w * base + base;
}

// ===========================================================================
extern "C" void kernel_launch(void* const* d_in, const int* in_sizes, int n_in,
                              void* d_out, int out_size, void* d_ws, size_t ws_size,
                              hipStream_t stream) {
    const float* ent   = (const float*)d_in[0];
    const float* uemb  = (const float*)d_in[1];
    const float* lat   = (const float*)d_in[2];
    const float* rel   = (const float*)d_in[3];
    const float* att   = (const float*)d_in[4];
    const float* vals  = (const float*)d_in[5];
    const int*   eidx  = (const int*)d_in[6];
    const int*   etype = (const int*)d_in[7];
    const int*   irows = (const int*)d_in[8];
    const int*   icols = (const int*)d_in[9];

    int nEnt = in_sizes[0] / D;
    int nU   = in_sizes[1] / D;
    int nF   = in_sizes[2] / D;
    int nRel = in_sizes[3] / D;
    int nnz  = in_sizes[5];
    int nE   = in_sizes[6] / 2;

    float* eagg = (float*)d_out;
    float* uagg = (float*)d_out + (size_t)nEnt * D;

    int NB_e = (nEnt + RPB - 1) / RPB;
    int NB_u = (nU + RPB - 1) / RPB;
    int cap_e = (nE / (NB_e > 0 ? NB_e : 1)) * 5 / 2 + 64;
    int cap_u = (nnz / (NB_u > 0 ? NB_u : 1)) * 5 / 2 + 64;

    // ---- workspace carve (256B-aligned) ----
    char* base = (char*)d_ws;
    size_t off = 0;
    auto carve = [&](size_t bytes) -> void* {
        void* r = base + off;
        off = (off + bytes + 255) & ~(size_t)255;
        return r;
    };
    float*          disen    = (float*)carve((size_t)nF * D * 4);
    unsigned short* entb     = (unsigned short*)carve((size_t)nEnt * D * 2);
    int*            g_cnt_e  = (int*)carve((size_t)NB_e * 4);   // contiguous zero-block:
    int*            g_cnt_u  = (int*)carve((size_t)NB_u * 4);   // g_cnt_e..ovcnt_e end
    int*            ovcnt_e  = (int*)carve((size_t)nEnt * 4);
    int*            region_e = (int*)carve((size_t)NB_e * cap_e * 4);
    int2*           region_u = (int2*)carve((size_t)NB_u * cap_u * 8);
    size_t need = off;

    bool fast = (ws_size >= need) && (nF == 4) && (nRel <= 32) &&
                (nEnt <= NB_MAX * RPB) && (nU <= NB_MAX * RPB) &&
                (nEnt <= (1 << 20)) && (nE > 0) && (nnz > 0);

    if (fast) {
        // zero: output (overflow base), counters span [g_cnt_e, region_e)
        hipMemsetAsync(d_out, 0, (size_t)out_size * sizeof(float), stream);
        size_t zspan = (size_t)((char*)region_e - (char*)g_cnt_e);
        hipMemsetAsync(g_cnt_e, 0, zspan, stream);

        disen_kernel<<<1, 64, 0, stream>>>(att, rel, disen, nF, nRel);
        {
            int total = nEnt * D;
            ent_to_bf16<<<(total + 255) / 256, 256, 0, stream>>>(ent, entb, total);
        }

        part_e<<<(nE + CHUNK - 1) / CHUNK, 256, 0, stream>>>(
            eidx, etype, nE, g_cnt_e, region_e, cap_e, ent, rel, eagg, ovcnt_e);
        part_u<<<(nnz + CHUNK - 1) / CHUNK, 256, 0, stream>>>(
            irows, icols, vals, nnz, g_cnt_u, region_u, cap_u, ent, uagg);

        agg_bkt<<<NB_u + NB_e, 256, 0, stream>>>(
            entb, rel, region_e, g_cnt_e, cap_e, ovcnt_e,
            region_u, g_cnt_u, cap_u,
            uemb, lat, disen, eagg, uagg, nEnt, nU, NB_u);
        return;
    }

    // ---- fallback: direct atomics (round-3 proven path) ----
    {
        float* cnt = (float*)d_ws;
        size_t cnt_bytes = (((size_t)nEnt * sizeof(float)) + 255) & ~(size_t)255;
        float* disen3 = (float*)((char*)d_ws + cnt_bytes);

        hipMemsetAsync(d_out, 0, (size_t)out_size * sizeof(float), stream);
        hipMemsetAsync(cnt, 0, (size_t)nEnt * sizeof(float), stream);

        disen_kernel<<<1, 64, 0, stream>>>(att, rel, disen3, nF, nRel);
        {
            long long total = (long long)nE * 64;
            kg_scatter<<<(int)((total + 255) / 256), 256, 0, stream>>>(
                ent, rel, eidx, etype, eagg, cnt, nE);
        }
        {
            long long total = (long long)nnz * 64;
            spmm_scatter<<<(int)((total + 255) / 256), 256, 0, stream>>>(
                ent, vals, irows, icols, uagg, nnz);
        }
        {
            int total = nEnt * D;
            ent_norm<<<(total + 255) / 256, 256, 0, stream>>>(eagg, cnt, total);
        }
        {
            long long total = (long long)nU * 64;
            user_final<<<(int)((total + 255) / 256), 256, 0, stream>>>(
                uemb, lat, disen3, uagg, nU);
        }
    }
}

// Round 13
// 858.162 us; speedup vs baseline: 1.0598x; 1.0598x over previous
//
#include <hip/hip_runtime.h>

#define D 64
#define RPB 128          // output rows per bucket (LDS tile)
#define NB_MAX 1024      // max buckets per side  -> nEnt,nU <= 131072
#define CHUNK 4096       // items per partition block
#define IPT 16           // items per thread (256*16 = 4096)

// ===========================================================================
// disen_weight = softmax(disen_weight_att, axis=-1) @ relation_emb   [F, D]
// ===========================================================================
__global__ void disen_kernel(const float* __restrict__ att, const float* __restrict__ rel,
                             float* __restrict__ disen, int nF, int nRel) {
    int d = threadIdx.x;
    if (d >= D) return;
    for (int f = 0; f < nF; ++f) {
        float m = -1e30f;
        for (int r = 0; r < nRel; ++r) m = fmaxf(m, att[f * nRel + r]);
        float sum = 0.0f, w = 0.0f;
        for (int r = 0; r < nRel; ++r) {
            float ex = __expf(att[f * nRel + r] - m);
            sum += ex;
            w   += ex * rel[r * D + d];
        }
        disen[f * D + d] = w / sum;
    }
}

// ===========================================================================
// entity_emb f32 -> bf16 (RNE): halves random-gather bytes in agg.
// ===========================================================================
__global__ void ent_to_bf16(const float* __restrict__ ent,
                            unsigned short* __restrict__ entb, int total) {
    int i = blockIdx.x * blockDim.x + threadIdx.x;
    if (i >= total) return;
    unsigned int u = __float_as_uint(ent[i]);
    u = u + 0x7FFFu + ((u >> 16) & 1u);
    entb[i] = (unsigned short)(u >> 16);
}

__device__ __forceinline__ float bf16_to_f32(unsigned short h) {
    return __uint_as_float(((unsigned int)h) << 16);
}

// ===========================================================================
// Partition (entities): bucket = head >> 7. LDS hist -> block scan ->
// one global atomic per (block,bucket) -> LDS reorder -> coalesced-run write.
// Payload int: tail(20) | type(5)<<20 | row_local(7)<<25.
// Overflow: direct f32 atomics into pre-zeroed eagg + ovcnt.
// ===========================================================================
__global__ void part_e(const int* __restrict__ eidx, const int* __restrict__ etype,
                       int nE, int* __restrict__ g_cnt, int* __restrict__ region,
                       int cap, const float* __restrict__ ent,
                       const float* __restrict__ rel, float* __restrict__ eagg,
                       int* __restrict__ ovcnt) {
    __shared__ int hist[NB_MAX], sA[NB_MAX], sB[NB_MAX], gbase[NB_MAX], lcur[NB_MAX];
    __shared__ int litems[CHUNK];
    __shared__ unsigned short lbkt[CHUNK];
    int tid = threadIdx.x;
    int c0 = blockIdx.x * CHUNK;
    int c1 = min(c0 + CHUNK, nE);

    for (int b = tid; b < NB_MAX; b += 256) hist[b] = 0;
    __syncthreads();
    for (int j = 0; j < IPT; ++j) {
        int i = c0 + j * 256 + tid;
        if (i < c1) atomicAdd(&hist[eidx[i] >> 7], 1);
    }
    __syncthreads();
    for (int b = tid; b < NB_MAX; b += 256) sA[b] = hist[b];
    __syncthreads();
    bool flip = false;
    for (int off = 1; off < NB_MAX; off <<= 1) {
        int* src = flip ? sB : sA;
        int* dst = flip ? sA : sB;
        for (int b = tid; b < NB_MAX; b += 256)
            dst[b] = src[b] + ((b >= off) ? src[b - off] : 0);
        __syncthreads();
        flip = !flip;
    }  // 10 iterations (even) -> final inclusive scan in sA
    for (int b = tid; b < NB_MAX; b += 256) {
        int h = hist[b];
        sB[b] = sA[b] - h;
        lcur[b] = 0;
        gbase[b] = h ? atomicAdd(&g_cnt[b], h) : 0;
    }
    __syncthreads();
    for (int j = 0; j < IPT; ++j) {
        int i = c0 + j * 256 + tid;
        if (i < c1) {
            int h = eidx[i];
            int b = h >> 7;
            unsigned rl = (unsigned)(h & 127);
            unsigned tail = (unsigned)eidx[nE + i];
            unsigned ty = (unsigned)etype[i];
            int payload = (int)(tail | (ty << 20) | (rl << 25));
            int rank = atomicAdd(&lcur[b], 1);
            int lpos = sB[b] + rank;
            litems[lpos] = payload;
            lbkt[lpos] = (unsigned short)b;
        }
    }
    __syncthreads();
    int cnt_chunk = c1 - c0;
    for (int j = tid; j < cnt_chunk; j += 256) {
        int b = lbkt[j];
        int payload = litems[j];
        int gpos = gbase[b] + (j - sB[b]);
        if (gpos < cap) {
            region[(size_t)b * cap + gpos] = payload;
        } else {
            unsigned p = (unsigned)payload;
            int tail = (int)(p & 0xFFFFF);
            int ty = (int)((p >> 20) & 31);
            int rl = (int)((p >> 25) & 127);
            int row = b * RPB + rl;
            for (int d = 0; d < D; ++d)
                atomicAdd(&eagg[(size_t)row * D + d],
                          ent[(size_t)tail * D + d] * rel[ty * D + d]);
            atomicAdd(&ovcnt[row], 1);
        }
    }
}

// ===========================================================================
// Partition (users): bucket = row >> 7. Payload int2{col | rl<<20, val_bits}.
// ===========================================================================
__global__ void part_u(const int* __restrict__ irows, const int* __restrict__ icols,
                       const float* __restrict__ vals, int nnz,
                       int* __restrict__ g_cnt, int2* __restrict__ region, int cap,
                       const float* __restrict__ ent, float* __restrict__ uagg) {
    __shared__ int hist[NB_MAX], sA[NB_MAX], sB[NB_MAX], gbase[NB_MAX], lcur[NB_MAX];
    __shared__ int2 litems[CHUNK];
    __shared__ unsigned short lbkt[CHUNK];
    int tid = threadIdx.x;
    int c0 = blockIdx.x * CHUNK;
    int c1 = min(c0 + CHUNK, nnz);

    for (int b = tid; b < NB_MAX; b += 256) hist[b] = 0;
    __syncthreads();
    for (int j = 0; j < IPT; ++j) {
        int i = c0 + j * 256 + tid;
        if (i < c1) atomicAdd(&hist[irows[i] >> 7], 1);
    }
    __syncthreads();
    for (int b = tid; b < NB_MAX; b += 256) sA[b] = hist[b];
    __syncthreads();
    bool flip = false;
    for (int off = 1; off < NB_MAX; off <<= 1) {
        int* src = flip ? sB : sA;
        int* dst = flip ? sA : sB;
        for (int b = tid; b < NB_MAX; b += 256)
            dst[b] = src[b] + ((b >= off) ? src[b - off] : 0);
        __syncthreads();
        flip = !flip;
    }
    for (int b = tid; b < NB_MAX; b += 256) {
        int h = hist[b];
        sB[b] = sA[b] - h;
        lcur[b] = 0;
        gbase[b] = h ? atomicAdd(&g_cnt[b], h) : 0;
    }
    __syncthreads();
    for (int j = 0; j < IPT; ++j) {
        int i = c0 + j * 256 + tid;
        if (i < c1) {
            int r = irows[i];
            int b = r >> 7;
            unsigned rl = (unsigned)(r & 127);
            int2 payload = make_int2((int)((unsigned)icols[i] | (rl << 20)),
                                     __float_as_int(vals[i]));
            int rank = atomicAdd(&lcur[b], 1);
            int lpos = sB[b] + rank;
            litems[lpos] = payload;
            lbkt[lpos] = (unsigned short)b;
        }
    }
    __syncthreads();
    int cnt_chunk = c1 - c0;
    for (int j = tid; j < cnt_chunk; j += 256) {
        int b = lbkt[j];
        int2 payload = litems[j];
        int gpos = gbase[b] + (j - sB[b]);
        if (gpos < cap) {
            region[(size_t)b * cap + gpos] = payload;
        } else {
            int col = payload.x & 0xFFFFF;
            int rl = (int)(((unsigned)payload.x >> 20) & 127);
            float v = __int_as_float(payload.y);
            int row = b * RPB + rl;
            for (int d = 0; d < D; ++d)
                atomicAdd(&uagg[(size_t)row * D + d],
                          ent[(size_t)col * D + d] * v);
        }
    }
}

// ===========================================================================
// Fused aggregation (R13 ILP fix): block per bucket; 128 rows in 32KB LDS.
// Each wave owns a CONTIGUOUS chunk of the bucket's items; the main loop is
// GUARD-FREE batches of 8 in three fully-unrolled passes (8 meta loads ->
// 8 gathers+mul -> 8 LDS atomics) so 8 gathers are genuinely in flight.
// __launch_bounds__(256,4) caps VGPR at 128 (room for the batch).
// ===========================================================================
__global__ __launch_bounds__(256, 4)
void agg_bkt(const unsigned short* __restrict__ entb,
             const float* __restrict__ rel,
             const int* __restrict__ region_e, const int* __restrict__ cnt_e,
             int cap_e, const int* __restrict__ ovcnt_e,
             const int2* __restrict__ region_u, const int* __restrict__ cnt_u,
             int cap_u,
             const float* __restrict__ uemb, const float* __restrict__ lat,
             const float* __restrict__ disen,
             float* __restrict__ eagg, float* __restrict__ uagg,
             int nEnt, int nU, int nbu) {
    __shared__ float acc[RPB * D];     // 32 KB
    __shared__ int rcnt[RPB];
    int tid = threadIdx.x;
    int wid = __builtin_amdgcn_readfirstlane(tid >> 6);
    int d = tid & 63;
    for (int idx = tid; idx < RPB * D; idx += 256) acc[idx] = 0.0f;
    for (int r = tid; r < RPB; r += 256) rcnt[r] = 0;
    __syncthreads();

    int b = blockIdx.x;
    if (b < nbu) {
        // ---------------- user bucket ----------------
        int n = min(cnt_u[b], cap_u);
        const int2* reg = region_u + (size_t)b * cap_u;
        int per = (n + 3) >> 2;               // contiguous chunk per wave
        int i0 = wid * per;
        int i1 = min(i0 + per, n);
        int k = i0;
        for (; k + 8 <= i1; k += 8) {
            int2 p[8];
#pragma unroll
            for (int j = 0; j < 8; ++j) p[j] = reg[k + j];
            float v[8];
#pragma unroll
            for (int j = 0; j < 8; ++j)
                v[j] = bf16_to_f32(entb[(size_t)(p[j].x & 0xFFFFF) * D + d]) *
                       __int_as_float(p[j].y);
#pragma unroll
            for (int j = 0; j < 8; ++j)
                atomicAdd(&acc[((((unsigned)p[j].x) >> 20) & 127) * D + d], v[j]);
        }
        for (; k < i1; ++k) {
            int2 p = reg[k];
            float v = bf16_to_f32(entb[(size_t)(p.x & 0xFFFFF) * D + d]) *
                      __int_as_float(p.y);
            atomicAdd(&acc[((((unsigned)p.x) >> 20) & 127) * D + d], v);
        }
        __syncthreads();
        // epilogue: wave handles 32 rows
        for (int r = wid * 32; r < wid * 32 + 32; ++r) {
            int R = b * RPB + r;
            if (R >= nU) continue;
            float aggv = acc[r * D + d] + uagg[(size_t)R * D + d];  // + overflow base
            float e = uemb[(size_t)R * D + d];
            float s[4];
#pragma unroll
            for (int f = 0; f < 4; ++f) {
                float p = e * lat[f * D + d];
#pragma unroll
                for (int off = 32; off > 0; off >>= 1) p += __shfl_xor(p, off, 64);
                s[f] = p;
            }
            float mx = fmaxf(fmaxf(s[0], s[1]), fmaxf(s[2], s[3]));
            float sum = 0.0f;
#pragma unroll
            for (int f = 0; f < 4; ++f) { s[f] = __expf(s[f] - mx); sum += s[f]; }
            float inv = 1.0f / sum;
            float watt = 0.0f;
#pragma unroll
            for (int f = 0; f < 4; ++f) watt += (s[f] * inv) * disen[f * D + d];
            uagg[(size_t)R * D + d] = watt * aggv + aggv;
        }
        return;
    }

    // ---------------- entity bucket ----------------
    int be = b - nbu;
    int n = min(cnt_e[be], cap_e);
    const int* reg = region_e + (size_t)be * cap_e;
    int per = (n + 3) >> 2;
    int i0 = wid * per;
    int i1 = min(i0 + per, n);
    int k = i0;
    for (; k + 8 <= i1; k += 8) {
        int p[8];
#pragma unroll
        for (int j = 0; j < 8; ++j) p[j] = reg[k + j];
        float v[8];
#pragma unroll
        for (int j = 0; j < 8; ++j) {
            unsigned pp = (unsigned)p[j];
            v[j] = bf16_to_f32(entb[(size_t)(pp & 0xFFFFF) * D + d]) *
                   rel[((pp >> 20) & 31) * D + d];
        }
#pragma unroll
        for (int j = 0; j < 8; ++j) {
            unsigned pp = (unsigned)p[j];
            int rl = (int)((pp >> 25) & 127);
            atomicAdd(&acc[rl * D + d], v[j]);
            if (d == 0) atomicAdd(&rcnt[rl], 1);
        }
    }
    for (; k < i1; ++k) {
        unsigned pp = (unsigned)reg[k];
        float v = bf16_to_f32(entb[(size_t)(pp & 0xFFFFF) * D + d]) *
                  rel[((pp >> 20) & 31) * D + d];
        int rl = (int)((pp >> 25) & 127);
        atomicAdd(&acc[rl * D + d], v);
        if (d == 0) atomicAdd(&rcnt[rl], 1);
    }
    __syncthreads();
    for (int idx = tid; idx < RPB * D; idx += 256) {
        int r = idx >> 6, dd = idx & 63;
        int R = be * RPB + r;
        if (R < nEnt) {
            float c = (float)(rcnt[r] + ovcnt_e[R]);
            size_t o = (size_t)R * D + dd;
            eagg[o] = (acc[idx] + eagg[o]) / fmaxf(c, 1.0f);  // + overflow base
        }
    }
}

// ===========================================================================
// FALLBACK: direct atomic scatter (round-3 proven path)
// ===========================================================================
__global__ void kg_scatter(const float* __restrict__ ent, const float* __restrict__ rel,
                           const int* __restrict__ eidx, const int* __restrict__ etype,
                           float* __restrict__ eagg, float* __restrict__ cnt, int nE) {
    int gid = blockIdx.x * blockDim.x + threadIdx.x;
    int e = gid >> 6;
    if (e >= nE) return;
    int d = gid & 63;
    int head = eidx[e];
    int tail = eidx[nE + e];
    int t = etype[e];
    float v = ent[tail * D + d] * rel[t * D + d];
    atomicAdd(&eagg[(size_t)head * D + d], v);
    if (d == 0) atomicAdd(&cnt[head], 1.0f);
}

__global__ void spmm_scatter(const float* __restrict__ ent, const float* __restrict__ vals,
                             const int* __restrict__ rows, const int* __restrict__ cols,
                             float* __restrict__ uagg, int nnz) {
    int gid = blockIdx.x * blockDim.x + threadIdx.x;
    int i = gid >> 6;
    if (i >= nnz) return;
    int d = gid & 63;
    float v = ent[cols[i] * D + d] * vals[i];
    atomicAdd(&uagg[(size_t)rows[i] * D + d], v);
}

__global__ void ent_norm(float* __restrict__ eagg, const float* __restrict__ cnt,
                         int total) {
    int gid = blockIdx.x * blockDim.x + threadIdx.x;
    if (gid >= total) return;
    float c = cnt[gid >> 6];
    eagg[gid] /= fmaxf(c, 1.0f);
}

__global__ void user_final(const float* __restrict__ uemb, const float* __restrict__ lat,
                           const float* __restrict__ disen, float* __restrict__ uagg,
                           int nU) {
    int gid = blockIdx.x * blockDim.x + threadIdx.x;
    int u = gid >> 6;
    if (u >= nU) return;
    int d = gid & 63;
    float e = uemb[(size_t)u * D + d];
    float s[4];
#pragma unroll
    for (int f = 0; f < 4; ++f) {
        float p = e * lat[f * D + d];
#pragma unroll
        for (int off = 32; off > 0; off >>= 1) p += __shfl_xor(p, off, 64);
        s[f] = p;
    }
    float m = fmaxf(fmaxf(s[0], s[1]), fmaxf(s[2], s[3]));
    float sum = 0.0f;
#pragma unroll
    for (int f = 0; f < 4; ++f) { s[f] = __expf(s[f] - m); sum += s[f]; }
    float inv = 1.0f / sum;
    float w = 0.0f;
#pragma unroll
    for (int f = 0; f < 4; ++f) w += (s[f] * inv) * disen[f * D + d];
    size_t o = (size_t)u * D + d;
    float base = uagg[o];
    uagg[o] = w * base + base;
}

// ===========================================================================
extern "C" void kernel_launch(void* const* d_in, const int* in_sizes, int n_in,
                              void* d_out, int out_size, void* d_ws, size_t ws_size,
                              hipStream_t stream) {
    const float* ent   = (const float*)d_in[0];
    const float* uemb  = (const float*)d_in[1];
    const float* lat   = (const float*)d_in[2];
    const float* rel   = (const float*)d_in[3];
    const float* att   = (const float*)d_in[4];
    const float* vals  = (const float*)d_in[5];
    const int*   eidx  = (const int*)d_in[6];
    const int*   etype = (const int*)d_in[7];
    const int*   irows = (const int*)d_in[8];
    const int*   icols = (const int*)d_in[9];

    int nEnt = in_sizes[0] / D;
    int nU   = in_sizes[1] / D;
    int nF   = in_sizes[2] / D;
    int nRel = in_sizes[3] / D;
    int nnz  = in_sizes[5];
    int nE   = in_sizes[6] / 2;

    float* eagg = (float*)d_out;
    float* uagg = (float*)d_out + (size_t)nEnt * D;

    int NB_e = (nEnt + RPB - 1) / RPB;
    int NB_u = (nU + RPB - 1) / RPB;
    int cap_e = (nE / (NB_e > 0 ? NB_e : 1)) * 5 / 2 + 64;
    int cap_u = (nnz / (NB_u > 0 ? NB_u : 1)) * 5 / 2 + 64;

    // ---- workspace carve (256B-aligned) ----
    char* base = (char*)d_ws;
    size_t off = 0;
    auto carve = [&](size_t bytes) -> void* {
        void* r = base + off;
        off = (off + bytes + 255) & ~(size_t)255;
        return r;
    };
    float*          disen    = (float*)carve((size_t)nF * D * 4);
    unsigned short* entb     = (unsigned short*)carve((size_t)nEnt * D * 2);
    int*            g_cnt_e  = (int*)carve((size_t)NB_e * 4);   // contiguous zero-block:
    int*            g_cnt_u  = (int*)carve((size_t)NB_u * 4);   // g_cnt_e..ovcnt_e end
    int*            ovcnt_e  = (int*)carve((size_t)nEnt * 4);
    int*            region_e = (int*)carve((size_t)NB_e * cap_e * 4);
    int2*           region_u = (int2*)carve((size_t)NB_u * cap_u * 8);
    size_t need = off;

    bool fast = (ws_size >= need) && (nF == 4) && (nRel <= 32) &&
                (nEnt <= NB_MAX * RPB) && (nU <= NB_MAX * RPB) &&
                (nEnt <= (1 << 20)) && (nE > 0) && (nnz > 0);

    if (fast) {
        // zero: output (overflow base), counters span [g_cnt_e, region_e)
        hipMemsetAsync(d_out, 0, (size_t)out_size * sizeof(float), stream);
        size_t zspan = (size_t)((char*)region_e - (char*)g_cnt_e);
        hipMemsetAsync(g_cnt_e, 0, zspan, stream);

        disen_kernel<<<1, 64, 0, stream>>>(att, rel, disen, nF, nRel);
        {
            int total = nEnt * D;
            ent_to_bf16<<<(total + 255) / 256, 256, 0, stream>>>(ent, entb, total);
        }

        part_e<<<(nE + CHUNK - 1) / CHUNK, 256, 0, stream>>>(
            eidx, etype, nE, g_cnt_e, region_e, cap_e, ent, rel, eagg, ovcnt_e);
        part_u<<<(nnz + CHUNK - 1) / CHUNK, 256, 0, stream>>>(
            irows, icols, vals, nnz, g_cnt_u, region_u, cap_u, ent, uagg);

        agg_bkt<<<NB_u + NB_e, 256, 0, stream>>>(
            entb, rel, region_e, g_cnt_e, cap_e, ovcnt_e,
            region_u, g_cnt_u, cap_u,
            uemb, lat, disen, eagg, uagg, nEnt, nU, NB_u);
        return;
    }

    // ---- fallback: direct atomics (round-3 proven path) ----
    {
        float* cnt = (float*)d_ws;
        size_t cnt_bytes = (((size_t)nEnt * sizeof(float)) + 255) & ~(size_t)255;
        float* disen3 = (float*)((char*)d_ws + cnt_bytes);

        hipMemsetAsync(d_out, 0, (size_t)out_size * sizeof(float), stream);
        hipMemsetAsync(cnt, 0, (size_t)nEnt * sizeof(float), stream);

        disen_kernel<<<1, 64, 0, stream>>>(att, rel, disen3, nF, nRel);
        {
            long long total = (long long)nE * 64;
            kg_scatter<<<(int)((total + 255) / 256), 256, 0, stream>>>(
                ent, rel, eidx, etype, eagg, cnt, nE);
        }
        {
            long long total = (long long)nnz * 64;
            spmm_scatter<<<(int)((total + 255) / 256), 256, 0, stream>>>(
                ent, vals, irows, icols, uagg, nnz);
        }
        {
            int total = nEnt * D;
            ent_norm<<<(total + 255) / 256, 256, 0, stream>>>(eagg, cnt, total);
        }
        {
            long long total = (long long)nU * 64;
            user_final<<<(int)((total + 255) / 256), 256, 0, stream>>>(
                uemb, lat, disen3, uagg, nU);
        }
    }
}

// Round 14
// 201.415 us; speedup vs baseline: 4.5153x; 4.2607x over previous
//
#include <hip/hip_runtime.h>

#define D 64
#define RPB 128          // output rows per bucket
#define NB_MAX 1024      // max buckets per side
#define CHUNK 4096       // items per partition block
#define IPT 16           // items per thread in partition
#define LCAP_E 3328      // LDS sort capacity (entity payloads, ints)
#define LCAP_U 6464      // LDS sort capacity (user payloads, int2)

// ===========================================================================
// disen_weight = softmax(disen_weight_att, axis=-1) @ relation_emb   [F, D]
// ===========================================================================
__global__ void disen_kernel(const float* __restrict__ att, const float* __restrict__ rel,
                             float* __restrict__ disen, int nF, int nRel) {
    int d = threadIdx.x;
    if (d >= D) return;
    for (int f = 0; f < nF; ++f) {
        float m = -1e30f;
        for (int r = 0; r < nRel; ++r) m = fmaxf(m, att[f * nRel + r]);
        float sum = 0.0f, w = 0.0f;
        for (int r = 0; r < nRel; ++r) {
            float ex = __expf(att[f * nRel + r] - m);
            sum += ex;
            w   += ex * rel[r * D + d];
        }
        disen[f * D + d] = w / sum;
    }
}

__global__ void ent_to_bf16(const float* __restrict__ ent,
                            unsigned short* __restrict__ entb, int total) {
    int i = blockIdx.x * blockDim.x + threadIdx.x;
    if (i >= total) return;
    unsigned int u = __float_as_uint(ent[i]);
    u = u + 0x7FFFu + ((u >> 16) & 1u);
    entb[i] = (unsigned short)(u >> 16);
}

__device__ __forceinline__ float bf16_to_f32(unsigned short h) {
    return __uint_as_float(((unsigned int)h) << 16);
}

// ===========================================================================
// PASS 1 (proven R12/R13): partition into 128-row buckets, coalesced runs.
// Entity payload: tail(20) | type(5)<<20 | row_local(7)<<25.
// ===========================================================================
__global__ void part_e(const int* __restrict__ eidx, const int* __restrict__ etype,
                       int nE, int* __restrict__ g_cnt, int* __restrict__ region,
                       int cap, const float* __restrict__ ent,
                       const float* __restrict__ rel, float* __restrict__ eagg,
                       int* __restrict__ ovcnt) {
    __shared__ int hist[NB_MAX], sA[NB_MAX], sB[NB_MAX], gbase[NB_MAX], lcur[NB_MAX];
    __shared__ int litems[CHUNK];
    __shared__ unsigned short lbkt[CHUNK];
    int tid = threadIdx.x;
    int c0 = blockIdx.x * CHUNK;
    int c1 = min(c0 + CHUNK, nE);

    for (int b = tid; b < NB_MAX; b += 256) hist[b] = 0;
    __syncthreads();
    for (int j = 0; j < IPT; ++j) {
        int i = c0 + j * 256 + tid;
        if (i < c1) atomicAdd(&hist[eidx[i] >> 7], 1);
    }
    __syncthreads();
    for (int b = tid; b < NB_MAX; b += 256) sA[b] = hist[b];
    __syncthreads();
    bool flip = false;
    for (int off = 1; off < NB_MAX; off <<= 1) {
        int* src = flip ? sB : sA;
        int* dst = flip ? sA : sB;
        for (int b = tid; b < NB_MAX; b += 256)
            dst[b] = src[b] + ((b >= off) ? src[b - off] : 0);
        __syncthreads();
        flip = !flip;
    }
    for (int b = tid; b < NB_MAX; b += 256) {
        int h = hist[b];
        sB[b] = sA[b] - h;
        lcur[b] = 0;
        gbase[b] = h ? atomicAdd(&g_cnt[b], h) : 0;
    }
    __syncthreads();
    for (int j = 0; j < IPT; ++j) {
        int i = c0 + j * 256 + tid;
        if (i < c1) {
            int h = eidx[i];
            int b = h >> 7;
            unsigned rl = (unsigned)(h & 127);
            unsigned tail = (unsigned)eidx[nE + i];
            unsigned ty = (unsigned)etype[i];
            int payload = (int)(tail | (ty << 20) | (rl << 25));
            int rank = atomicAdd(&lcur[b], 1);
            int lpos = sB[b] + rank;
            litems[lpos] = payload;
            lbkt[lpos] = (unsigned short)b;
        }
    }
    __syncthreads();
    int cnt_chunk = c1 - c0;
    for (int j = tid; j < cnt_chunk; j += 256) {
        int b = lbkt[j];
        int payload = litems[j];
        int gpos = gbase[b] + (j - sB[b]);
        if (gpos < cap) {
            region[(size_t)b * cap + gpos] = payload;
        } else {
            unsigned p = (unsigned)payload;
            int tail = (int)(p & 0xFFFFF);
            int ty = (int)((p >> 20) & 31);
            int rl = (int)((p >> 25) & 127);
            int row = b * RPB + rl;
            for (int d = 0; d < D; ++d)
                atomicAdd(&eagg[(size_t)row * D + d],
                          ent[(size_t)tail * D + d] * rel[ty * D + d]);
            atomicAdd(&ovcnt[row], 1);
        }
    }
}

__global__ void part_u(const int* __restrict__ irows, const int* __restrict__ icols,
                       const float* __restrict__ vals, int nnz,
                       int* __restrict__ g_cnt, int2* __restrict__ region, int cap,
                       const float* __restrict__ ent, float* __restrict__ uagg) {
    __shared__ int hist[NB_MAX], sA[NB_MAX], sB[NB_MAX], gbase[NB_MAX], lcur[NB_MAX];
    __shared__ int2 litems[CHUNK];
    __shared__ unsigned short lbkt[CHUNK];
    int tid = threadIdx.x;
    int c0 = blockIdx.x * CHUNK;
    int c1 = min(c0 + CHUNK, nnz);

    for (int b = tid; b < NB_MAX; b += 256) hist[b] = 0;
    __syncthreads();
    for (int j = 0; j < IPT; ++j) {
        int i = c0 + j * 256 + tid;
        if (i < c1) atomicAdd(&hist[irows[i] >> 7], 1);
    }
    __syncthreads();
    for (int b = tid; b < NB_MAX; b += 256) sA[b] = hist[b];
    __syncthreads();
    bool flip = false;
    for (int off = 1; off < NB_MAX; off <<= 1) {
        int* src = flip ? sB : sA;
        int* dst = flip ? sA : sB;
        for (int b = tid; b < NB_MAX; b += 256)
            dst[b] = src[b] + ((b >= off) ? src[b - off] : 0);
        __syncthreads();
        flip = !flip;
    }
    for (int b = tid; b < NB_MAX; b += 256) {
        int h = hist[b];
        sB[b] = sA[b] - h;
        lcur[b] = 0;
        gbase[b] = h ? atomicAdd(&g_cnt[b], h) : 0;
    }
    __syncthreads();
    for (int j = 0; j < IPT; ++j) {
        int i = c0 + j * 256 + tid;
        if (i < c1) {
            int r = irows[i];
            int b = r >> 7;
            unsigned rl = (unsigned)(r & 127);
            int2 payload = make_int2((int)((unsigned)icols[i] | (rl << 20)),
                                     __float_as_int(vals[i]));
            int rank = atomicAdd(&lcur[b], 1);
            int lpos = sB[b] + rank;
            litems[lpos] = payload;
            lbkt[lpos] = (unsigned short)b;
        }
    }
    __syncthreads();
    int cnt_chunk = c1 - c0;
    for (int j = tid; j < cnt_chunk; j += 256) {
        int b = lbkt[j];
        int2 payload = litems[j];
        int gpos = gbase[b] + (j - sB[b]);
        if (gpos < cap) {
            region[(size_t)b * cap + gpos] = payload;
        } else {
            int col = payload.x & 0xFFFFF;
            int rl = (int)(((unsigned)payload.x >> 20) & 127);
            float v = __int_as_float(payload.y);
            int row = b * RPB + rl;
            for (int d = 0; d < D; ++d)
                atomicAdd(&uagg[(size_t)row * D + d],
                          ent[(size_t)col * D + d] * v);
        }
    }
}

// ===========================================================================
// PASS 2 (new): in-place within-bucket counting sort by row_local.
// All global traffic coalesced (read -> LDS count; read -> LDS scatter;
// LDS -> coalesced write-back). Emits rs[R] = {start_in_region, count}.
// ===========================================================================
__global__ void sort_e(int* __restrict__ region, const int* __restrict__ g_cnt,
                       int cap, int2* __restrict__ rs, int nEnt) {
    __shared__ int buf[LCAP_E];
    __shared__ int rcnt[RPB], rbase[RPB], rtick[RPB];
    int b = blockIdx.x;
    int tid = threadIdx.x;
    int n = min(g_cnt[b], cap);
    int* reg = region + (size_t)b * cap;

    for (int r = tid; r < RPB; r += 256) { rcnt[r] = 0; rtick[r] = 0; }
    __syncthreads();
    for (int j = tid; j < n; j += 256)
        atomicAdd(&rcnt[(((unsigned)reg[j]) >> 25) & 127], 1);
    __syncthreads();
    if (tid == 0) {
        int a = 0;
        for (int r = 0; r < RPB; ++r) { rbase[r] = a; a += rcnt[r]; }
    }
    __syncthreads();
    for (int r = tid; r < RPB; r += 256) {
        int R = b * RPB + r;
        if (R < nEnt) rs[R] = make_int2(b * cap + rbase[r], rcnt[r]);
    }
    for (int j = tid; j < n; j += 256) {
        int p = reg[j];
        int rl = (((unsigned)p) >> 25) & 127;
        buf[rbase[rl] + atomicAdd(&rtick[rl], 1)] = p;
    }
    __syncthreads();
    for (int j = tid; j < n; j += 256) reg[j] = buf[j];
}

__global__ void sort_u(int2* __restrict__ region, const int* __restrict__ g_cnt,
                       int cap, int2* __restrict__ rs, int nU) {
    __shared__ int2 buf[LCAP_U];
    __shared__ int rcnt[RPB], rbase[RPB], rtick[RPB];
    int b = blockIdx.x;
    int tid = threadIdx.x;
    int n = min(g_cnt[b], cap);
    int2* reg = region + (size_t)b * cap;

    for (int r = tid; r < RPB; r += 256) { rcnt[r] = 0; rtick[r] = 0; }
    __syncthreads();
    for (int j = tid; j < n; j += 256)
        atomicAdd(&rcnt[(((unsigned)reg[j].x) >> 20) & 127], 1);
    __syncthreads();
    if (tid == 0) {
        int a = 0;
        for (int r = 0; r < RPB; ++r) { rbase[r] = a; a += rcnt[r]; }
    }
    __syncthreads();
    for (int r = tid; r < RPB; r += 256) {
        int R = b * RPB + r;
        if (R < nU) rs[R] = make_int2(b * cap + rbase[r], rcnt[r]);
    }
    for (int j = tid; j < n; j += 256) {
        int2 p = reg[j];
        int rl = (((unsigned)p.x) >> 20) & 127;
        buf[rbase[rl] + atomicAdd(&rtick[rl], 1)] = p;
    }
    __syncthreads();
    for (int j = tid; j < n; j += 256) reg[j] = buf[j];
}

// ===========================================================================
// PASS 3: wave-per-row aggregation over CONTIGUOUS payload runs (150k waves).
// Users first (fused softmax epilogue), then entities (fused mean).
// Only random traffic: the bf16 entity-row gathers, 4-deep guard-free batches.
// ===========================================================================
__global__ void agg_csr(const unsigned short* __restrict__ entb,
                        const float* __restrict__ rel,
                        const int* __restrict__ region_e, const int2* __restrict__ rs_e,
                        const int* __restrict__ ovcnt_e,
                        const int2* __restrict__ region_u, const int2* __restrict__ rs_u,
                        const float* __restrict__ uemb, const float* __restrict__ lat,
                        const float* __restrict__ disen,
                        float* __restrict__ eagg, float* __restrict__ uagg,
                        int nEnt, int nU) {
    int gid = blockIdx.x * blockDim.x + threadIdx.x;
    int row = gid >> 6;
    int d = gid & 63;

    if (row < nU) {
        int2 r = rs_u[row];
        int k = r.x, end = r.x + r.y;
        float a0 = 0.f, a1 = 0.f, a2 = 0.f, a3 = 0.f;
        for (; k + 4 <= end; k += 4) {
            int2 p0 = region_u[k], p1 = region_u[k + 1];
            int2 p2 = region_u[k + 2], p3 = region_u[k + 3];
            a0 += bf16_to_f32(entb[(size_t)(p0.x & 0xFFFFF) * D + d]) * __int_as_float(p0.y);
            a1 += bf16_to_f32(entb[(size_t)(p1.x & 0xFFFFF) * D + d]) * __int_as_float(p1.y);
            a2 += bf16_to_f32(entb[(size_t)(p2.x & 0xFFFFF) * D + d]) * __int_as_float(p2.y);
            a3 += bf16_to_f32(entb[(size_t)(p3.x & 0xFFFFF) * D + d]) * __int_as_float(p3.y);
        }
        for (; k < end; ++k) {
            int2 p0 = region_u[k];
            a0 += bf16_to_f32(entb[(size_t)(p0.x & 0xFFFFF) * D + d]) * __int_as_float(p0.y);
        }
        float agg = ((a0 + a1) + (a2 + a3)) + uagg[(size_t)row * D + d];  // + overflow base

        float e = uemb[(size_t)row * D + d];
        float s[4];
#pragma unroll
        for (int f = 0; f < 4; ++f) {
            float p = e * lat[f * D + d];
#pragma unroll
            for (int off = 32; off > 0; off >>= 1) p += __shfl_xor(p, off, 64);
            s[f] = p;
        }
        float m = fmaxf(fmaxf(s[0], s[1]), fmaxf(s[2], s[3]));
        float sum = 0.0f;
#pragma unroll
        for (int f = 0; f < 4; ++f) { s[f] = __expf(s[f] - m); sum += s[f]; }
        float inv = 1.0f / sum;
        float w = 0.0f;
#pragma unroll
        for (int f = 0; f < 4; ++f) w += (s[f] * inv) * disen[f * D + d];

        uagg[(size_t)row * D + d] = w * agg + agg;
        return;
    }

    int R = row - nU;
    if (R >= nEnt) return;
    int2 r = rs_e[R];
    int k = r.x, end = r.x + r.y;
    float a0 = 0.f, a1 = 0.f, a2 = 0.f, a3 = 0.f;
    for (; k + 4 <= end; k += 4) {
        unsigned p0 = (unsigned)region_e[k],     p1 = (unsigned)region_e[k + 1];
        unsigned p2 = (unsigned)region_e[k + 2], p3 = (unsigned)region_e[k + 3];
        a0 += bf16_to_f32(entb[(size_t)(p0 & 0xFFFFF) * D + d]) * rel[((p0 >> 20) & 31) * D + d];
        a1 += bf16_to_f32(entb[(size_t)(p1 & 0xFFFFF) * D + d]) * rel[((p1 >> 20) & 31) * D + d];
        a2 += bf16_to_f32(entb[(size_t)(p2 & 0xFFFFF) * D + d]) * rel[((p2 >> 20) & 31) * D + d];
        a3 += bf16_to_f32(entb[(size_t)(p3 & 0xFFFFF) * D + d]) * rel[((p3 >> 20) & 31) * D + d];
    }
    for (; k < end; ++k) {
        unsigned p0 = (unsigned)region_e[k];
        a0 += bf16_to_f32(entb[(size_t)(p0 & 0xFFFFF) * D + d]) * rel[((p0 >> 20) & 31) * D + d];
    }
    float c = (float)(r.y + ovcnt_e[R]);
    size_t o = (size_t)R * D + d;
    eagg[o] = (((a0 + a1) + (a2 + a3)) + eagg[o]) / fmaxf(c, 1.0f);  // + overflow base
}

// ===========================================================================
// FALLBACK: direct atomic scatter (round-3 proven path)
// ===========================================================================
__global__ void kg_scatter(const float* __restrict__ ent, const float* __restrict__ rel,
                           const int* __restrict__ eidx, const int* __restrict__ etype,
                           float* __restrict__ eagg, float* __restrict__ cnt, int nE) {
    int gid = blockIdx.x * blockDim.x + threadIdx.x;
    int e = gid >> 6;
    if (e >= nE) return;
    int d = gid & 63;
    int head = eidx[e];
    int tail = eidx[nE + e];
    int t = etype[e];
    float v = ent[tail * D + d] * rel[t * D + d];
    atomicAdd(&eagg[(size_t)head * D + d], v);
    if (d == 0) atomicAdd(&cnt[head], 1.0f);
}

__global__ void spmm_scatter(const float* __restrict__ ent, const float* __restrict__ vals,
                             const int* __restrict__ rows, const int* __restrict__ cols,
                             float* __restrict__ uagg, int nnz) {
    int gid = blockIdx.x * blockDim.x + threadIdx.x;
    int i = gid >> 6;
    if (i >= nnz) return;
    int d = gid & 63;
    float v = ent[cols[i] * D + d] * vals[i];
    atomicAdd(&uagg[(size_t)rows[i] * D + d], v);
}

__global__ void ent_norm(float* __restrict__ eagg, const float* __restrict__ cnt,
                         int total) {
    int gid = blockIdx.x * blockDim.x + threadIdx.x;
    if (gid >= total) return;
    float c = cnt[gid >> 6];
    eagg[gid] /= fmaxf(c, 1.0f);
}

__global__ void user_final(const float* __restrict__ uemb, const float* __restrict__ lat,
                           const float* __restrict__ disen, float* __restrict__ uagg,
                           int nU) {
    int gid = blockIdx.x * blockDim.x + threadIdx.x;
    int u = gid >> 6;
    if (u >= nU) return;
    int d = gid & 63;
    float e = uemb[(size_t)u * D + d];
    float s[4];
#pragma unroll
    for (int f = 0; f < 4; ++f) {
        float p = e * lat[f * D + d];
#pragma unroll
        for (int off = 32; off > 0; off >>= 1) p += __shfl_xor(p, off, 64);
        s[f] = p;
    }
    float m = fmaxf(fmaxf(s[0], s[1]), fmaxf(s[2], s[3]));
    float sum = 0.0f;
#pragma unroll
    for (int f = 0; f < 4; ++f) { s[f] = __expf(s[f] - m); sum += s[f]; }
    float inv = 1.0f / sum;
    float w = 0.0f;
#pragma unroll
    for (int f = 0; f < 4; ++f) w += (s[f] * inv) * disen[f * D + d];
    size_t o = (size_t)u * D + d;
    float base = uagg[o];
    uagg[o] = w * base + base;
}

// ===========================================================================
extern "C" void kernel_launch(void* const* d_in, const int* in_sizes, int n_in,
                              void* d_out, int out_size, void* d_ws, size_t ws_size,
                              hipStream_t stream) {
    const float* ent   = (const float*)d_in[0];
    const float* uemb  = (const float*)d_in[1];
    const float* lat   = (const float*)d_in[2];
    const float* rel   = (const float*)d_in[3];
    const float* att   = (const float*)d_in[4];
    const float* vals  = (const float*)d_in[5];
    const int*   eidx  = (const int*)d_in[6];
    const int*   etype = (const int*)d_in[7];
    const int*   irows = (const int*)d_in[8];
    const int*   icols = (const int*)d_in[9];

    int nEnt = in_sizes[0] / D;
    int nU   = in_sizes[1] / D;
    int nF   = in_sizes[2] / D;
    int nRel = in_sizes[3] / D;
    int nnz  = in_sizes[5];
    int nE   = in_sizes[6] / 2;

    float* eagg = (float*)d_out;
    float* uagg = (float*)d_out + (size_t)nEnt * D;

    int NB_e = (nEnt + RPB - 1) / RPB;
    int NB_u = (nU + RPB - 1) / RPB;
    int cap_e = (nE / (NB_e > 0 ? NB_e : 1)) * 5 / 2 + 64;
    int cap_u = (nnz / (NB_u > 0 ? NB_u : 1)) * 5 / 2 + 64;

    // ---- workspace carve (256B-aligned) ----
    char* base = (char*)d_ws;
    size_t off = 0;
    auto carve = [&](size_t bytes) -> void* {
        void* r = base + off;
        off = (off + bytes + 255) & ~(size_t)255;
        return r;
    };
    float*          disen    = (float*)carve((size_t)nF * D * 4);
    unsigned short* entb     = (unsigned short*)carve((size_t)nEnt * D * 2);
    int*            g_cnt_e  = (int*)carve((size_t)NB_e * 4);   // zero-span start
    int*            g_cnt_u  = (int*)carve((size_t)NB_u * 4);
    int*            ovcnt_e  = (int*)carve((size_t)nEnt * 4);   // zero-span end
    int2*           rs_e     = (int2*)carve((size_t)nEnt * 8);
    int2*           rs_u     = (int2*)carve((size_t)nU * 8);
    int*            region_e = (int*)carve((size_t)NB_e * cap_e * 4);
    int2*           region_u = (int2*)carve((size_t)NB_u * cap_u * 8);
    size_t need = off;

    bool fast = (ws_size >= need) && (nF == 4) && (nRel <= 32) &&
                (nEnt <= NB_MAX * RPB) && (nU <= NB_MAX * RPB) &&
                (nEnt <= (1 << 20)) && (cap_e <= LCAP_E) && (cap_u <= LCAP_U) &&
                (nE > 0) && (nnz > 0);

    if (fast) {
        hipMemsetAsync(d_out, 0, (size_t)out_size * sizeof(float), stream);  // overflow base
        size_t zspan = (size_t)((char*)rs_e - (char*)g_cnt_e);
        hipMemsetAsync(g_cnt_e, 0, zspan, stream);

        disen_kernel<<<1, 64, 0, stream>>>(att, rel, disen, nF, nRel);
        {
            int total = nEnt * D;
            ent_to_bf16<<<(total + 255) / 256, 256, 0, stream>>>(ent, entb, total);
        }

        part_e<<<(nE + CHUNK - 1) / CHUNK, 256, 0, stream>>>(
            eidx, etype, nE, g_cnt_e, region_e, cap_e, ent, rel, eagg, ovcnt_e);
        part_u<<<(nnz + CHUNK - 1) / CHUNK, 256, 0, stream>>>(
            irows, icols, vals, nnz, g_cnt_u, region_u, cap_u, ent, uagg);

        sort_e<<<NB_e, 256, 0, stream>>>(region_e, g_cnt_e, cap_e, rs_e, nEnt);
        sort_u<<<NB_u, 256, 0, stream>>>(region_u, g_cnt_u, cap_u, rs_u, nU);

        long long rows = (long long)nEnt + nU;
        long long tot = rows * 64;
        agg_csr<<<(int)((tot + 255) / 256), 256, 0, stream>>>(
            entb, rel, region_e, rs_e, ovcnt_e, region_u, rs_u,
            uemb, lat, disen, eagg, uagg, nEnt, nU);
        return;
    }

    // ---- fallback: direct atomics (round-3 proven path) ----
    {
        float* cnt = (float*)d_ws;
        size_t cnt_bytes = (((size_t)nEnt * sizeof(float)) + 255) & ~(size_t)255;
        float* disen3 = (float*)((char*)d_ws + cnt_bytes);

        hipMemsetAsync(d_out, 0, (size_t)out_size * sizeof(float), stream);
        hipMemsetAsync(cnt, 0, (size_t)nEnt * sizeof(float), stream);

        disen_kernel<<<1, 64, 0, stream>>>(att, rel, disen3, nF, nRel);
        {
            long long total = (long long)nE * 64;
            kg_scatter<<<(int)((total + 255) / 256), 256, 0, stream>>>(
                ent, rel, eidx, etype, eagg, cnt, nE);
        }
        {
            long long total = (long long)nnz * 64;
            spmm_scatter<<<(int)((total + 255) / 256), 256, 0, stream>>>(
                ent, vals, irows, icols, uagg, nnz);
        }
        {
            int total = nEnt * D;
            ent_norm<<<(total + 255) / 256, 256, 0, stream>>>(eagg, cnt, total);
        }
        {
            long long total = (long long)nU * 64;
            user_final<<<(int)((total + 255) / 256), 256, 0, stream>>>(
                uemb, lat, disen3, uagg, nU);
        }
    }
}

// Round 15
// 175.865 us; speedup vs baseline: 5.1712x; 1.1453x over previous
//
#include <hip/hip_runtime.h>

#define D 64
#define RPB 128          // output rows per bucket
#define NB_MAX 1024      // max buckets per side
#define CHUNK 2048       // items per partition block (R15: was 4096; 2x blocks -> phase overlap)
#define IPT 8            // items per thread in partition
#define LCAP_E 3328      // LDS sort capacity (entity payloads, ints)
#define LCAP_U 6464      // LDS sort capacity (user payloads, int2)

// ===========================================================================
// disen_weight = softmax(disen_weight_att, axis=-1) @ relation_emb   [F, D]
// ===========================================================================
__global__ void disen_kernel(const float* __restrict__ att, const float* __restrict__ rel,
                             float* __restrict__ disen, int nF, int nRel) {
    int d = threadIdx.x;
    if (d >= D) return;
    for (int f = 0; f < nF; ++f) {
        float m = -1e30f;
        for (int r = 0; r < nRel; ++r) m = fmaxf(m, att[f * nRel + r]);
        float sum = 0.0f, w = 0.0f;
        for (int r = 0; r < nRel; ++r) {
            float ex = __expf(att[f * nRel + r] - m);
            sum += ex;
            w   += ex * rel[r * D + d];
        }
        disen[f * D + d] = w / sum;
    }
}

// f32 -> bf16 (RNE), vectorized 4-wide (nEnt*D is a multiple of 64)
__global__ void ent_to_bf16(const float4* __restrict__ ent4,
                            ushort4* __restrict__ entb4, int total4) {
    int i = blockIdx.x * blockDim.x + threadIdx.x;
    if (i >= total4) return;
    float4 v = ent4[i];
    ushort4 o;
    unsigned u;
    u = __float_as_uint(v.x); u += 0x7FFFu + ((u >> 16) & 1u); o.x = (unsigned short)(u >> 16);
    u = __float_as_uint(v.y); u += 0x7FFFu + ((u >> 16) & 1u); o.y = (unsigned short)(u >> 16);
    u = __float_as_uint(v.z); u += 0x7FFFu + ((u >> 16) & 1u); o.z = (unsigned short)(u >> 16);
    u = __float_as_uint(v.w); u += 0x7FFFu + ((u >> 16) & 1u); o.w = (unsigned short)(u >> 16);
    entb4[i] = o;
}

__device__ __forceinline__ float bf16_to_f32(unsigned short h) {
    return __uint_as_float(((unsigned int)h) << 16);
}

// ===========================================================================
// PASS 1: partition into 128-row buckets, coalesced runs (proven R12-R14).
// Entity payload: tail(20) | type(5)<<20 | row_local(7)<<25.
// Overflow (~never): direct f32 atomics into pre-zeroed output + flag.
// ===========================================================================
__global__ void part_e(const int* __restrict__ eidx, const int* __restrict__ etype,
                       int nE, int* __restrict__ g_cnt, int* __restrict__ region,
                       int cap, const float* __restrict__ ent,
                       const float* __restrict__ rel, float* __restrict__ eagg,
                       int* __restrict__ ovcnt, int* __restrict__ ovflag) {
    __shared__ int hist[NB_MAX], sA[NB_MAX], sB[NB_MAX], gbase[NB_MAX], lcur[NB_MAX];
    __shared__ int litems[CHUNK];
    __shared__ unsigned short lbkt[CHUNK];
    int tid = threadIdx.x;
    int c0 = blockIdx.x * CHUNK;
    int c1 = min(c0 + CHUNK, nE);

    for (int b = tid; b < NB_MAX; b += 256) hist[b] = 0;
    __syncthreads();
    for (int j = 0; j < IPT; ++j) {
        int i = c0 + j * 256 + tid;
        if (i < c1) atomicAdd(&hist[eidx[i] >> 7], 1);
    }
    __syncthreads();
    for (int b = tid; b < NB_MAX; b += 256) sA[b] = hist[b];
    __syncthreads();
    bool flip = false;
    for (int off = 1; off < NB_MAX; off <<= 1) {
        int* src = flip ? sB : sA;
        int* dst = flip ? sA : sB;
        for (int b = tid; b < NB_MAX; b += 256)
            dst[b] = src[b] + ((b >= off) ? src[b - off] : 0);
        __syncthreads();
        flip = !flip;
    }  // 10 iterations (even) -> inclusive scan ends in sA
    for (int b = tid; b < NB_MAX; b += 256) {
        int h = hist[b];
        sB[b] = sA[b] - h;
        lcur[b] = 0;
        gbase[b] = h ? atomicAdd(&g_cnt[b], h) : 0;
    }
    __syncthreads();
    for (int j = 0; j < IPT; ++j) {
        int i = c0 + j * 256 + tid;
        if (i < c1) {
            int h = eidx[i];
            int b = h >> 7;
            unsigned rl = (unsigned)(h & 127);
            unsigned tail = (unsigned)eidx[nE + i];
            unsigned ty = (unsigned)etype[i];
            int payload = (int)(tail | (ty << 20) | (rl << 25));
            int rank = atomicAdd(&lcur[b], 1);
            int lpos = sB[b] + rank;
            litems[lpos] = payload;
            lbkt[lpos] = (unsigned short)b;
        }
    }
    __syncthreads();
    int cnt_chunk = c1 - c0;
    for (int j = tid; j < cnt_chunk; j += 256) {
        int b = lbkt[j];
        int payload = litems[j];
        int gpos = gbase[b] + (j - sB[b]);
        if (gpos < cap) {
            region[(size_t)b * cap + gpos] = payload;
        } else {
            unsigned p = (unsigned)payload;
            int tail = (int)(p & 0xFFFFF);
            int ty = (int)((p >> 20) & 31);
            int rl = (int)((p >> 25) & 127);
            int row = b * RPB + rl;
            for (int d = 0; d < D; ++d)
                atomicAdd(&eagg[(size_t)row * D + d],
                          ent[(size_t)tail * D + d] * rel[ty * D + d]);
            atomicAdd(&ovcnt[row], 1);
            atomicAdd(&ovflag[0], 1);
        }
    }
}

__global__ void part_u(const int* __restrict__ irows, const int* __restrict__ icols,
                       const float* __restrict__ vals, int nnz,
                       int* __restrict__ g_cnt, int2* __restrict__ region, int cap,
                       const float* __restrict__ ent, float* __restrict__ uagg,
                       int* __restrict__ ovflag) {
    __shared__ int hist[NB_MAX], sA[NB_MAX], sB[NB_MAX], gbase[NB_MAX], lcur[NB_MAX];
    __shared__ int2 litems[CHUNK];
    __shared__ unsigned short lbkt[CHUNK];
    int tid = threadIdx.x;
    int c0 = blockIdx.x * CHUNK;
    int c1 = min(c0 + CHUNK, nnz);

    for (int b = tid; b < NB_MAX; b += 256) hist[b] = 0;
    __syncthreads();
    for (int j = 0; j < IPT; ++j) {
        int i = c0 + j * 256 + tid;
        if (i < c1) atomicAdd(&hist[irows[i] >> 7], 1);
    }
    __syncthreads();
    for (int b = tid; b < NB_MAX; b += 256) sA[b] = hist[b];
    __syncthreads();
    bool flip = false;
    for (int off = 1; off < NB_MAX; off <<= 1) {
        int* src = flip ? sB : sA;
        int* dst = flip ? sA : sB;
        for (int b = tid; b < NB_MAX; b += 256)
            dst[b] = src[b] + ((b >= off) ? src[b - off] : 0);
        __syncthreads();
        flip = !flip;
    }
    for (int b = tid; b < NB_MAX; b += 256) {
        int h = hist[b];
        sB[b] = sA[b] - h;
        lcur[b] = 0;
        gbase[b] = h ? atomicAdd(&g_cnt[b], h) : 0;
    }
    __syncthreads();
    for (int j = 0; j < IPT; ++j) {
        int i = c0 + j * 256 + tid;
        if (i < c1) {
            int r = irows[i];
            int b = r >> 7;
            unsigned rl = (unsigned)(r & 127);
            int2 payload = make_int2((int)((unsigned)icols[i] | (rl << 20)),
                                     __float_as_int(vals[i]));
            int rank = atomicAdd(&lcur[b], 1);
            int lpos = sB[b] + rank;
            litems[lpos] = payload;
            lbkt[lpos] = (unsigned short)b;
        }
    }
    __syncthreads();
    int cnt_chunk = c1 - c0;
    for (int j = tid; j < cnt_chunk; j += 256) {
        int b = lbkt[j];
        int2 payload = litems[j];
        int gpos = gbase[b] + (j - sB[b]);
        if (gpos < cap) {
            region[(size_t)b * cap + gpos] = payload;
        } else {
            int col = payload.x & 0xFFFFF;
            int rl = (int)(((unsigned)payload.x >> 20) & 127);
            float v = __int_as_float(payload.y);
            int row = b * RPB + rl;
            for (int d = 0; d < D; ++d)
                atomicAdd(&uagg[(size_t)row * D + d],
                          ent[(size_t)col * D + d] * v);
            atomicAdd(&ovflag[1], 1);
        }
    }
}

// ===========================================================================
// PASS 2: in-place within-bucket counting sort by row_local (proven R14).
// Emits rs[R] = {start_in_region, count}.
// ===========================================================================
__global__ void sort_e(int* __restrict__ region, const int* __restrict__ g_cnt,
                       int cap, int2* __restrict__ rs, int nEnt) {
    __shared__ int buf[LCAP_E];
    __shared__ int rcnt[RPB], rbase[RPB], rtick[RPB];
    int b = blockIdx.x;
    int tid = threadIdx.x;
    int n = min(g_cnt[b], cap);
    int* reg = region + (size_t)b * cap;

    for (int r = tid; r < RPB; r += 256) { rcnt[r] = 0; rtick[r] = 0; }
    __syncthreads();
    for (int j = tid; j < n; j += 256)
        atomicAdd(&rcnt[(((unsigned)reg[j]) >> 25) & 127], 1);
    __syncthreads();
    if (tid == 0) {
        int a = 0;
        for (int r = 0; r < RPB; ++r) { rbase[r] = a; a += rcnt[r]; }
    }
    __syncthreads();
    for (int r = tid; r < RPB; r += 256) {
        int R = b * RPB + r;
        if (R < nEnt) rs[R] = make_int2(b * cap + rbase[r], rcnt[r]);
    }
    for (int j = tid; j < n; j += 256) {
        int p = reg[j];
        int rl = (((unsigned)p) >> 25) & 127;
        buf[rbase[rl] + atomicAdd(&rtick[rl], 1)] = p;
    }
    __syncthreads();
    for (int j = tid; j < n; j += 256) reg[j] = buf[j];
}

__global__ void sort_u(int2* __restrict__ region, const int* __restrict__ g_cnt,
                       int cap, int2* __restrict__ rs, int nU) {
    __shared__ int2 buf[LCAP_U];
    __shared__ int rcnt[RPB], rbase[RPB], rtick[RPB];
    int b = blockIdx.x;
    int tid = threadIdx.x;
    int n = min(g_cnt[b], cap);
    int2* reg = region + (size_t)b * cap;

    for (int r = tid; r < RPB; r += 256) { rcnt[r] = 0; rtick[r] = 0; }
    __syncthreads();
    for (int j = tid; j < n; j += 256)
        atomicAdd(&rcnt[(((unsigned)reg[j].x) >> 20) & 127], 1);
    __syncthreads();
    if (tid == 0) {
        int a = 0;
        for (int r = 0; r < RPB; ++r) { rbase[r] = a; a += rcnt[r]; }
    }
    __syncthreads();
    for (int r = tid; r < RPB; r += 256) {
        int R = b * RPB + r;
        if (R < nU) rs[R] = make_int2(b * cap + rbase[r], rcnt[r]);
    }
    for (int j = tid; j < n; j += 256) {
        int2 p = reg[j];
        int rl = (((unsigned)p.x) >> 20) & 127;
        buf[rbase[rl] + atomicAdd(&rtick[rl], 1)] = p;
    }
    __syncthreads();
    for (int j = tid; j < n; j += 256) reg[j] = buf[j];
}

// ===========================================================================
// PASS 3: wave-per-row aggregation over contiguous runs.
// R15: row via readfirstlane -> rs/payload/ovcnt loads are provably
// wave-uniform (scalar s_load path) -> vmem transactions ~halve.
// Overflow base reads gated by ovflag (never taken for in-cap data).
// ===========================================================================
__global__ void agg_csr(const unsigned short* __restrict__ entb,
                        const float* __restrict__ rel,
                        const int* __restrict__ region_e, const int2* __restrict__ rs_e,
                        const int* __restrict__ ovcnt_e,
                        const int2* __restrict__ region_u, const int2* __restrict__ rs_u,
                        const int* __restrict__ ovflag,
                        const float* __restrict__ uemb, const float* __restrict__ lat,
                        const float* __restrict__ disen,
                        float* __restrict__ eagg, float* __restrict__ uagg,
                        int nEnt, int nU) {
    int gid = blockIdx.x * blockDim.x + threadIdx.x;
    int row = __builtin_amdgcn_readfirstlane(gid >> 6);   // wave-uniform, provable
    int d = gid & 63;

    if (row < nU) {
        int2 r = rs_u[row];
        int k = r.x, end = r.x + r.y;
        float a0 = 0.f, a1 = 0.f, a2 = 0.f, a3 = 0.f;
        for (; k + 4 <= end; k += 4) {
            int2 p0 = region_u[k], p1 = region_u[k + 1];
            int2 p2 = region_u[k + 2], p3 = region_u[k + 3];
            a0 += bf16_to_f32(entb[(size_t)(p0.x & 0xFFFFF) * D + d]) * __int_as_float(p0.y);
            a1 += bf16_to_f32(entb[(size_t)(p1.x & 0xFFFFF) * D + d]) * __int_as_float(p1.y);
            a2 += bf16_to_f32(entb[(size_t)(p2.x & 0xFFFFF) * D + d]) * __int_as_float(p2.y);
            a3 += bf16_to_f32(entb[(size_t)(p3.x & 0xFFFFF) * D + d]) * __int_as_float(p3.y);
        }
        for (; k < end; ++k) {
            int2 p0 = region_u[k];
            a0 += bf16_to_f32(entb[(size_t)(p0.x & 0xFFFFF) * D + d]) * __int_as_float(p0.y);
        }
        float agg = ((a0 + a1) + (a2 + a3));
        if (ovflag[1] != 0) agg += uagg[(size_t)row * D + d];   // overflow base (rare)

        float e = uemb[(size_t)row * D + d];
        float s[4];
#pragma unroll
        for (int f = 0; f < 4; ++f) {
            float p = e * lat[f * D + d];
#pragma unroll
            for (int off = 32; off > 0; off >>= 1) p += __shfl_xor(p, off, 64);
            s[f] = p;
        }
        float m = fmaxf(fmaxf(s[0], s[1]), fmaxf(s[2], s[3]));
        float sum = 0.0f;
#pragma unroll
        for (int f = 0; f < 4; ++f) { s[f] = __expf(s[f] - m); sum += s[f]; }
        float inv = 1.0f / sum;
        float w = 0.0f;
#pragma unroll
        for (int f = 0; f < 4; ++f) w += (s[f] * inv) * disen[f * D + d];

        uagg[(size_t)row * D + d] = w * agg + agg;
        return;
    }

    int R = row - nU;
    if (R >= nEnt) return;
    int2 r = rs_e[R];
    int k = r.x, end = r.x + r.y;
    float a0 = 0.f, a1 = 0.f, a2 = 0.f, a3 = 0.f;
    for (; k + 4 <= end; k += 4) {
        unsigned p0 = (unsigned)region_e[k],     p1 = (unsigned)region_e[k + 1];
        unsigned p2 = (unsigned)region_e[k + 2], p3 = (unsigned)region_e[k + 3];
        a0 += bf16_to_f32(entb[(size_t)(p0 & 0xFFFFF) * D + d]) * rel[((p0 >> 20) & 31) * D + d];
        a1 += bf16_to_f32(entb[(size_t)(p1 & 0xFFFFF) * D + d]) * rel[((p1 >> 20) & 31) * D + d];
        a2 += bf16_to_f32(entb[(size_t)(p2 & 0xFFFFF) * D + d]) * rel[((p2 >> 20) & 31) * D + d];
        a3 += bf16_to_f32(entb[(size_t)(p3 & 0xFFFFF) * D + d]) * rel[((p3 >> 20) & 31) * D + d];
    }
    for (; k < end; ++k) {
        unsigned p0 = (unsigned)region_e[k];
        a0 += bf16_to_f32(entb[(size_t)(p0 & 0xFFFFF) * D + d]) * rel[((p0 >> 20) & 31) * D + d];
    }
    float sumv = ((a0 + a1) + (a2 + a3));
    float c = (float)r.y;
    size_t o = (size_t)R * D + d;
    if (ovflag[0] != 0) {                       // overflow base (rare)
        sumv += eagg[o];
        c += (float)ovcnt_e[R];
    }
    eagg[o] = sumv / fmaxf(c, 1.0f);
}

// ===========================================================================
// FALLBACK: direct atomic scatter (round-3 proven path)
// ===========================================================================
__global__ void kg_scatter(const float* __restrict__ ent, const float* __restrict__ rel,
                           const int* __restrict__ eidx, const int* __restrict__ etype,
                           float* __restrict__ eagg, float* __restrict__ cnt, int nE) {
    int gid = blockIdx.x * blockDim.x + threadIdx.x;
    int e = gid >> 6;
    if (e >= nE) return;
    int d = gid & 63;
    int head = eidx[e];
    int tail = eidx[nE + e];
    int t = etype[e];
    float v = ent[tail * D + d] * rel[t * D + d];
    atomicAdd(&eagg[(size_t)head * D + d], v);
    if (d == 0) atomicAdd(&cnt[head], 1.0f);
}

__global__ void spmm_scatter(const float* __restrict__ ent, const float* __restrict__ vals,
                             const int* __restrict__ rows, const int* __restrict__ cols,
                             float* __restrict__ uagg, int nnz) {
    int gid = blockIdx.x * blockDim.x + threadIdx.x;
    int i = gid >> 6;
    if (i >= nnz) return;
    int d = gid & 63;
    float v = ent[cols[i] * D + d] * vals[i];
    atomicAdd(&uagg[(size_t)rows[i] * D + d], v);
}

__global__ void ent_norm(float* __restrict__ eagg, const float* __restrict__ cnt,
                         int total) {
    int gid = blockIdx.x * blockDim.x + threadIdx.x;
    if (gid >= total) return;
    float c = cnt[gid >> 6];
    eagg[gid] /= fmaxf(c, 1.0f);
}

__global__ void user_final(const float* __restrict__ uemb, const float* __restrict__ lat,
                           const float* __restrict__ disen, float* __restrict__ uagg,
                           int nU) {
    int gid = blockIdx.x * blockDim.x + threadIdx.x;
    int u = gid >> 6;
    if (u >= nU) return;
    int d = gid & 63;
    float e = uemb[(size_t)u * D + d];
    float s[4];
#pragma unroll
    for (int f = 0; f < 4; ++f) {
        float p = e * lat[f * D + d];
#pragma unroll
        for (int off = 32; off > 0; off >>= 1) p += __shfl_xor(p, off, 64);
        s[f] = p;
    }
    float m = fmaxf(fmaxf(s[0], s[1]), fmaxf(s[2], s[3]));
    float sum = 0.0f;
#pragma unroll
    for (int f = 0; f < 4; ++f) { s[f] = __expf(s[f] - m); sum += s[f]; }
    float inv = 1.0f / sum;
    float w = 0.0f;
#pragma unroll
    for (int f = 0; f < 4; ++f) w += (s[f] * inv) * disen[f * D + d];
    size_t o = (size_t)u * D + d;
    float base = uagg[o];
    uagg[o] = w * base + base;
}

// ===========================================================================
extern "C" void kernel_launch(void* const* d_in, const int* in_sizes, int n_in,
                              void* d_out, int out_size, void* d_ws, size_t ws_size,
                              hipStream_t stream) {
    const float* ent   = (const float*)d_in[0];
    const float* uemb  = (const float*)d_in[1];
    const float* lat   = (const float*)d_in[2];
    const float* rel   = (const float*)d_in[3];
    const float* att   = (const float*)d_in[4];
    const float* vals  = (const float*)d_in[5];
    const int*   eidx  = (const int*)d_in[6];
    const int*   etype = (const int*)d_in[7];
    const int*   irows = (const int*)d_in[8];
    const int*   icols = (const int*)d_in[9];

    int nEnt = in_sizes[0] / D;
    int nU   = in_sizes[1] / D;
    int nF   = in_sizes[2] / D;
    int nRel = in_sizes[3] / D;
    int nnz  = in_sizes[5];
    int nE   = in_sizes[6] / 2;

    float* eagg = (float*)d_out;
    float* uagg = (float*)d_out + (size_t)nEnt * D;

    int NB_e = (nEnt + RPB - 1) / RPB;
    int NB_u = (nU + RPB - 1) / RPB;
    int cap_e = (nE / (NB_e > 0 ? NB_e : 1)) * 5 / 2 + 64;
    int cap_u = (nnz / (NB_u > 0 ? NB_u : 1)) * 5 / 2 + 64;

    // ---- workspace carve (256B-aligned) ----
    char* base = (char*)d_ws;
    size_t off = 0;
    auto carve = [&](size_t bytes) -> void* {
        void* r = base + off;
        off = (off + bytes + 255) & ~(size_t)255;
        return r;
    };
    float*          disen    = (float*)carve((size_t)nF * D * 4);
    unsigned short* entb     = (unsigned short*)carve((size_t)nEnt * D * 2);
    int*            g_cnt_e  = (int*)carve((size_t)NB_e * 4);   // zero-span start
    int*            g_cnt_u  = (int*)carve((size_t)NB_u * 4);
    int*            ovflag   = (int*)carve(2 * 4);
    int*            ovcnt_e  = (int*)carve((size_t)nEnt * 4);   // zero-span end
    int2*           rs_e     = (int2*)carve((size_t)nEnt * 8);
    int2*           rs_u     = (int2*)carve((size_t)nU * 8);
    int*            region_e = (int*)carve((size_t)NB_e * cap_e * 4);
    int2*           region_u = (int2*)carve((size_t)NB_u * cap_u * 8);
    size_t need = off;

    bool fast = (ws_size >= need) && (nF == 4) && (nRel <= 32) &&
                (nEnt <= NB_MAX * RPB) && (nU <= NB_MAX * RPB) &&
                (nEnt <= (1 << 20)) && (cap_e <= LCAP_E) && (cap_u <= LCAP_U) &&
                (nE > 0) && (nnz > 0);

    if (fast) {
        hipMemsetAsync(d_out, 0, (size_t)out_size * sizeof(float), stream);  // overflow base
        size_t zspan = (size_t)((char*)rs_e - (char*)g_cnt_e);
        hipMemsetAsync(g_cnt_e, 0, zspan, stream);

        disen_kernel<<<1, 64, 0, stream>>>(att, rel, disen, nF, nRel);
        {
            int total4 = nEnt * D / 4;
            ent_to_bf16<<<(total4 + 255) / 256, 256, 0, stream>>>(
                (const float4*)ent, (ushort4*)entb, total4);
        }

        part_e<<<(nE + CHUNK - 1) / CHUNK, 256, 0, stream>>>(
            eidx, etype, nE, g_cnt_e, region_e, cap_e, ent, rel, eagg, ovcnt_e, ovflag);
        part_u<<<(nnz + CHUNK - 1) / CHUNK, 256, 0, stream>>>(
            irows, icols, vals, nnz, g_cnt_u, region_u, cap_u, ent, uagg, ovflag);

        sort_e<<<NB_e, 256, 0, stream>>>(region_e, g_cnt_e, cap_e, rs_e, nEnt);
        sort_u<<<NB_u, 256, 0, stream>>>(region_u, g_cnt_u, cap_u, rs_u, nU);

        long long rows = (long long)nEnt + nU;
        long long tot = rows * 64;
        agg_csr<<<(int)((tot + 255) / 256), 256, 0, stream>>>(
            entb, rel, region_e, rs_e, ovcnt_e, region_u, rs_u, ovflag,
            uemb, lat, disen, eagg, uagg, nEnt, nU);
        return;
    }

    // ---- fallback: direct atomics (round-3 proven path) ----
    {
        float* cnt = (float*)d_ws;
        size_t cnt_bytes = (((size_t)nEnt * sizeof(float)) + 255) & ~(size_t)255;
        float* disen3 = (float*)((char*)d_ws + cnt_bytes);

        hipMemsetAsync(d_out, 0, (size_t)out_size * sizeof(float), stream);
        hipMemsetAsync(cnt, 0, (size_t)nEnt * sizeof(float), stream);

        disen_kernel<<<1, 64, 0, stream>>>(att, rel, disen3, nF, nRel);
        {
            long long total = (long long)nE * 64;
            kg_scatter<<<(int)((total + 255) / 256), 256, 0, stream>>>(
                ent, rel, eidx, etype, eagg, cnt, nE);
        }
        {
            long long total = (long long)nnz * 64;
            spmm_scatter<<<(int)((total + 255) / 256), 256, 0, stream>>>(
                ent, vals, irows, icols, uagg, nnz);
        }
        {
            int total = nEnt * D;
            ent_norm<<<(total + 255) / 256, 256, 0, stream>>>(eagg, cnt, total);
        }
        {
            long long total = (long long)nU * 64;
            user_final<<<(int)((total + 255) / 256), 256, 0, stream>>>(
                uemb, lat, disen3, uagg, nU);
        }
    }
}

// Round 16
// 149.516 us; speedup vs baseline: 6.0826x; 1.1762x over previous
//
#include <hip/hip_runtime.h>

#define D 64
#define RPB 128          // output rows per bucket
#define NB_MAX 1024      // max buckets per side
#define CHUNK 4096       // items per partition block (runs avg 4 -> fewer scatter txns)
#define IPT 16           // items per thread in partition
#define LCAP_E 3328      // LDS sort capacity (entity payloads, ints)
#define LCAP_U 6464      // LDS sort capacity (user payloads, int2)

__device__ __forceinline__ float bf16_to_f32(unsigned short h) {
    return __uint_as_float(((unsigned int)h) << 16);
}

// ===========================================================================
// PREP (fused): blocks [0,nconv) convert entity_emb f32->bf16 (RNE, 4-wide);
// block nconv computes disen = softmax(att) @ rel.
// ===========================================================================
__global__ void prep(const float4* __restrict__ ent4, ushort4* __restrict__ entb4,
                     int total4, const float* __restrict__ att,
                     const float* __restrict__ rel, float* __restrict__ disen,
                     int nF, int nRel, int nconv) {
    if ((int)blockIdx.x == nconv) {
        int d = threadIdx.x;
        if (d >= D) return;
        for (int f = 0; f < nF; ++f) {
            float m = -1e30f;
            for (int r = 0; r < nRel; ++r) m = fmaxf(m, att[f * nRel + r]);
            float sum = 0.0f, w = 0.0f;
            for (int r = 0; r < nRel; ++r) {
                float ex = __expf(att[f * nRel + r] - m);
                sum += ex;
                w   += ex * rel[r * D + d];
            }
            disen[f * D + d] = w / sum;
        }
        return;
    }
    int i = blockIdx.x * 256 + threadIdx.x;
    if (i >= total4) return;
    float4 v = ent4[i];
    ushort4 o;
    unsigned u;
    u = __float_as_uint(v.x); u += 0x7FFFu + ((u >> 16) & 1u); o.x = (unsigned short)(u >> 16);
    u = __float_as_uint(v.y); u += 0x7FFFu + ((u >> 16) & 1u); o.y = (unsigned short)(u >> 16);
    u = __float_as_uint(v.z); u += 0x7FFFu + ((u >> 16) & 1u); o.z = (unsigned short)(u >> 16);
    u = __float_as_uint(v.w); u += 0x7FFFu + ((u >> 16) & 1u); o.w = (unsigned short)(u >> 16);
    entb4[i] = o;
}

// ===========================================================================
// PART (fused): blocks [0,nbe) partition KG edges; blocks [nbe,nbe+nbu)
// partition interactions. Dynamic LDS (60KB): 5 hist arrays + payload + bkt.
// Both sides co-resident -> phase latencies overlap.
// Entity payload: tail(20) | type(5)<<20 | row_local(7)<<25.
// Overflow (~never): direct f32 atomics into pre-zeroed output + flag.
// ===========================================================================
__global__ void part_both(const int* __restrict__ eidx, const int* __restrict__ etype,
                          int nE, int nbe,
                          const int* __restrict__ irows, const int* __restrict__ icols,
                          const float* __restrict__ vals, int nnz,
                          int* __restrict__ g_cnt_e, int* __restrict__ region_e, int cap_e,
                          int* __restrict__ g_cnt_u, int2* __restrict__ region_u, int cap_u,
                          const float* __restrict__ ent, const float* __restrict__ rel,
                          float* __restrict__ eagg, float* __restrict__ uagg,
                          int* __restrict__ ovcnt, int* __restrict__ ovflag) {
    extern __shared__ char smem[];
    int* hist  = (int*)smem;
    int* sA    = hist  + NB_MAX;
    int* sB    = sA    + NB_MAX;
    int* gbase = sB    + NB_MAX;
    int* lcur  = gbase + NB_MAX;
    char* pay  = (char*)(lcur + NB_MAX);          // CHUNK*8 max
    int tid = threadIdx.x;

    if ((int)blockIdx.x < nbe) {
        // ---------------- entity side ----------------
        int* litems = (int*)pay;
        unsigned short* lbkt = (unsigned short*)(litems + CHUNK);
        int c0 = blockIdx.x * CHUNK;
        int c1 = min(c0 + CHUNK, nE);

        for (int b = tid; b < NB_MAX; b += 256) hist[b] = 0;
        __syncthreads();
        for (int j = 0; j < IPT; ++j) {
            int i = c0 + j * 256 + tid;
            if (i < c1) atomicAdd(&hist[eidx[i] >> 7], 1);
        }
        __syncthreads();
        for (int b = tid; b < NB_MAX; b += 256) sA[b] = hist[b];
        __syncthreads();
        bool flip = false;
        for (int off = 1; off < NB_MAX; off <<= 1) {
            int* src = flip ? sB : sA;
            int* dst = flip ? sA : sB;
            for (int b = tid; b < NB_MAX; b += 256)
                dst[b] = src[b] + ((b >= off) ? src[b - off] : 0);
            __syncthreads();
            flip = !flip;
        }  // 10 iters (even) -> inclusive scan in sA
        for (int b = tid; b < NB_MAX; b += 256) {
            int h = hist[b];
            sB[b] = sA[b] - h;
            lcur[b] = 0;
            gbase[b] = h ? atomicAdd(&g_cnt_e[b], h) : 0;
        }
        __syncthreads();
        for (int j = 0; j < IPT; ++j) {
            int i = c0 + j * 256 + tid;
            if (i < c1) {
                int h = eidx[i];
                int b = h >> 7;
                unsigned rl = (unsigned)(h & 127);
                unsigned tail = (unsigned)eidx[nE + i];
                unsigned ty = (unsigned)etype[i];
                int payload = (int)(tail | (ty << 20) | (rl << 25));
                int rank = atomicAdd(&lcur[b], 1);
                int lpos = sB[b] + rank;
                litems[lpos] = payload;
                lbkt[lpos] = (unsigned short)b;
            }
        }
        __syncthreads();
        int cnt_chunk = c1 - c0;
        for (int j = tid; j < cnt_chunk; j += 256) {
            int b = lbkt[j];
            int payload = litems[j];
            int gpos = gbase[b] + (j - sB[b]);
            if (gpos < cap_e) {
                region_e[(size_t)b * cap_e + gpos] = payload;
            } else {
                unsigned p = (unsigned)payload;
                int tail = (int)(p & 0xFFFFF);
                int ty = (int)((p >> 20) & 31);
                int rl = (int)((p >> 25) & 127);
                int row = b * RPB + rl;
                for (int d = 0; d < D; ++d)
                    atomicAdd(&eagg[(size_t)row * D + d],
                              ent[(size_t)tail * D + d] * rel[ty * D + d]);
                atomicAdd(&ovcnt[row], 1);
                atomicAdd(&ovflag[0], 1);
            }
        }
        return;
    }

    // ---------------- user side ----------------
    {
        int2* litems = (int2*)pay;
        unsigned short* lbkt = (unsigned short*)(litems + CHUNK);
        int c0 = ((int)blockIdx.x - nbe) * CHUNK;
        int c1 = min(c0 + CHUNK, nnz);

        for (int b = tid; b < NB_MAX; b += 256) hist[b] = 0;
        __syncthreads();
        for (int j = 0; j < IPT; ++j) {
            int i = c0 + j * 256 + tid;
            if (i < c1) atomicAdd(&hist[irows[i] >> 7], 1);
        }
        __syncthreads();
        for (int b = tid; b < NB_MAX; b += 256) sA[b] = hist[b];
        __syncthreads();
        bool flip = false;
        for (int off = 1; off < NB_MAX; off <<= 1) {
            int* src = flip ? sB : sA;
            int* dst = flip ? sA : sB;
            for (int b = tid; b < NB_MAX; b += 256)
                dst[b] = src[b] + ((b >= off) ? src[b - off] : 0);
            __syncthreads();
            flip = !flip;
        }
        for (int b = tid; b < NB_MAX; b += 256) {
            int h = hist[b];
            sB[b] = sA[b] - h;
            lcur[b] = 0;
            gbase[b] = h ? atomicAdd(&g_cnt_u[b], h) : 0;
        }
        __syncthreads();
        for (int j = 0; j < IPT; ++j) {
            int i = c0 + j * 256 + tid;
            if (i < c1) {
                int r = irows[i];
                int b = r >> 7;
                unsigned rl = (unsigned)(r & 127);
                int2 payload = make_int2((int)((unsigned)icols[i] | (rl << 20)),
                                         __float_as_int(vals[i]));
                int rank = atomicAdd(&lcur[b], 1);
                int lpos = sB[b] + rank;
                litems[lpos] = payload;
                lbkt[lpos] = (unsigned short)b;
            }
        }
        __syncthreads();
        int cnt_chunk = c1 - c0;
        for (int j = tid; j < cnt_chunk; j += 256) {
            int b = lbkt[j];
            int2 payload = litems[j];
            int gpos = gbase[b] + (j - sB[b]);
            if (gpos < cap_u) {
                region_u[(size_t)b * cap_u + gpos] = payload;
            } else {
                int col = payload.x & 0xFFFFF;
                int rl = (int)(((unsigned)payload.x >> 20) & 127);
                float v = __int_as_float(payload.y);
                int row = b * RPB + rl;
                for (int d = 0; d < D; ++d)
                    atomicAdd(&uagg[(size_t)row * D + d],
                              ent[(size_t)col * D + d] * v);
                atomicAdd(&ovflag[1], 1);
            }
        }
    }
}

// ===========================================================================
// SORT (fused): blocks [0,NB_e) sort entity buckets; [NB_e, NB_e+NB_u) user.
// In-place within-bucket counting sort by row_local; all global traffic
// coalesced. Emits rs[R] = {start_in_region, count}. Dynamic LDS (52KB).
// ===========================================================================
__global__ void sort_both(int* __restrict__ region_e, const int* __restrict__ g_cnt_e,
                          int cap_e, int2* __restrict__ rs_e, int nEnt, int NB_e,
                          int2* __restrict__ region_u, const int* __restrict__ g_cnt_u,
                          int cap_u, int2* __restrict__ rs_u, int nU) {
    extern __shared__ char smem[];
    int* rcnt  = (int*)smem;
    int* rbase = rcnt + RPB;
    int* rtick = rbase + RPB;
    char* bufc = (char*)(rtick + RPB);
    int tid = threadIdx.x;

    if ((int)blockIdx.x < NB_e) {
        int b = blockIdx.x;
        int* buf = (int*)bufc;
        int n = min(g_cnt_e[b], cap_e);
        int* reg = region_e + (size_t)b * cap_e;

        for (int r = tid; r < RPB; r += 256) { rcnt[r] = 0; rtick[r] = 0; }
        __syncthreads();
        for (int j = tid; j < n; j += 256)
            atomicAdd(&rcnt[(((unsigned)reg[j]) >> 25) & 127], 1);
        __syncthreads();
        if (tid == 0) {
            int a = 0;
            for (int r = 0; r < RPB; ++r) { rbase[r] = a; a += rcnt[r]; }
        }
        __syncthreads();
        for (int r = tid; r < RPB; r += 256) {
            int R = b * RPB + r;
            if (R < nEnt) rs_e[R] = make_int2(b * cap_e + rbase[r], rcnt[r]);
        }
        for (int j = tid; j < n; j += 256) {
            int p = reg[j];
            int rl = (((unsigned)p) >> 25) & 127;
            buf[rbase[rl] + atomicAdd(&rtick[rl], 1)] = p;
        }
        __syncthreads();
        for (int j = tid; j < n; j += 256) reg[j] = buf[j];
        return;
    }

    {
        int b = blockIdx.x - NB_e;
        int2* buf = (int2*)bufc;
        int n = min(g_cnt_u[b], cap_u);
        int2* reg = region_u + (size_t)b * cap_u;

        for (int r = tid; r < RPB; r += 256) { rcnt[r] = 0; rtick[r] = 0; }
        __syncthreads();
        for (int j = tid; j < n; j += 256)
            atomicAdd(&rcnt[(((unsigned)reg[j].x) >> 20) & 127], 1);
        __syncthreads();
        if (tid == 0) {
            int a = 0;
            for (int r = 0; r < RPB; ++r) { rbase[r] = a; a += rcnt[r]; }
        }
        __syncthreads();
        for (int r = tid; r < RPB; r += 256) {
            int R = b * RPB + r;
            if (R < nU) rs_u[R] = make_int2(b * cap_u + rbase[r], rcnt[r]);
        }
        for (int j = tid; j < n; j += 256) {
            int2 p = reg[j];
            int rl = (((unsigned)p.x) >> 20) & 127;
            buf[rbase[rl] + atomicAdd(&rtick[rl], 1)] = p;
        }
        __syncthreads();
        for (int j = tid; j < n; j += 256) reg[j] = buf[j];
    }
}

// ===========================================================================
// AGG (unchanged from R15, at the measured 26 G random-transaction ceiling):
// wave-per-row over contiguous runs; row via readfirstlane -> uniform loads
// take the scalar path; overflow base reads gated by ovflag.
// ===========================================================================
__global__ void agg_csr(const unsigned short* __restrict__ entb,
                        const float* __restrict__ rel,
                        const int* __restrict__ region_e, const int2* __restrict__ rs_e,
                        const int* __restrict__ ovcnt_e,
                        const int2* __restrict__ region_u, const int2* __restrict__ rs_u,
                        const int* __restrict__ ovflag,
                        const float* __restrict__ uemb, const float* __restrict__ lat,
                        const float* __restrict__ disen,
                        float* __restrict__ eagg, float* __restrict__ uagg,
                        int nEnt, int nU) {
    int gid = blockIdx.x * blockDim.x + threadIdx.x;
    int row = __builtin_amdgcn_readfirstlane(gid >> 6);
    int d = gid & 63;

    if (row < nU) {
        int2 r = rs_u[row];
        int k = r.x, end = r.x + r.y;
        float a0 = 0.f, a1 = 0.f, a2 = 0.f, a3 = 0.f;
        for (; k + 4 <= end; k += 4) {
            int2 p0 = region_u[k], p1 = region_u[k + 1];
            int2 p2 = region_u[k + 2], p3 = region_u[k + 3];
            a0 += bf16_to_f32(entb[(size_t)(p0.x & 0xFFFFF) * D + d]) * __int_as_float(p0.y);
            a1 += bf16_to_f32(entb[(size_t)(p1.x & 0xFFFFF) * D + d]) * __int_as_float(p1.y);
            a2 += bf16_to_f32(entb[(size_t)(p2.x & 0xFFFFF) * D + d]) * __int_as_float(p2.y);
            a3 += bf16_to_f32(entb[(size_t)(p3.x & 0xFFFFF) * D + d]) * __int_as_float(p3.y);
        }
        for (; k < end; ++k) {
            int2 p0 = region_u[k];
            a0 += bf16_to_f32(entb[(size_t)(p0.x & 0xFFFFF) * D + d]) * __int_as_float(p0.y);
        }
        float agg = ((a0 + a1) + (a2 + a3));
        if (ovflag[1] != 0) agg += uagg[(size_t)row * D + d];

        float e = uemb[(size_t)row * D + d];
        float s[4];
#pragma unroll
        for (int f = 0; f < 4; ++f) {
            float p = e * lat[f * D + d];
#pragma unroll
            for (int off = 32; off > 0; off >>= 1) p += __shfl_xor(p, off, 64);
            s[f] = p;
        }
        float m = fmaxf(fmaxf(s[0], s[1]), fmaxf(s[2], s[3]));
        float sum = 0.0f;
#pragma unroll
        for (int f = 0; f < 4; ++f) { s[f] = __expf(s[f] - m); sum += s[f]; }
        float inv = 1.0f / sum;
        float w = 0.0f;
#pragma unroll
        for (int f = 0; f < 4; ++f) w += (s[f] * inv) * disen[f * D + d];

        uagg[(size_t)row * D + d] = w * agg + agg;
        return;
    }

    int R = row - nU;
    if (R >= nEnt) return;
    int2 r = rs_e[R];
    int k = r.x, end = r.x + r.y;
    float a0 = 0.f, a1 = 0.f, a2 = 0.f, a3 = 0.f;
    for (; k + 4 <= end; k += 4) {
        unsigned p0 = (unsigned)region_e[k],     p1 = (unsigned)region_e[k + 1];
        unsigned p2 = (unsigned)region_e[k + 2], p3 = (unsigned)region_e[k + 3];
        a0 += bf16_to_f32(entb[(size_t)(p0 & 0xFFFFF) * D + d]) * rel[((p0 >> 20) & 31) * D + d];
        a1 += bf16_to_f32(entb[(size_t)(p1 & 0xFFFFF) * D + d]) * rel[((p1 >> 20) & 31) * D + d];
        a2 += bf16_to_f32(entb[(size_t)(p2 & 0xFFFFF) * D + d]) * rel[((p2 >> 20) & 31) * D + d];
        a3 += bf16_to_f32(entb[(size_t)(p3 & 0xFFFFF) * D + d]) * rel[((p3 >> 20) & 31) * D + d];
    }
    for (; k < end; ++k) {
        unsigned p0 = (unsigned)region_e[k];
        a0 += bf16_to_f32(entb[(size_t)(p0 & 0xFFFFF) * D + d]) * rel[((p0 >> 20) & 31) * D + d];
    }
    float sumv = ((a0 + a1) + (a2 + a3));
    float c = (float)r.y;
    size_t o = (size_t)R * D + d;
    if (ovflag[0] != 0) {
        sumv += eagg[o];
        c += (float)ovcnt_e[R];
    }
    eagg[o] = sumv / fmaxf(c, 1.0f);
}

// ===========================================================================
// FALLBACK: direct atomic scatter (round-3 proven path)
// ===========================================================================
__global__ void disen_kernel(const float* __restrict__ att, const float* __restrict__ rel,
                             float* __restrict__ disen, int nF, int nRel) {
    int d = threadIdx.x;
    if (d >= D) return;
    for (int f = 0; f < nF; ++f) {
        float m = -1e30f;
        for (int r = 0; r < nRel; ++r) m = fmaxf(m, att[f * nRel + r]);
        float sum = 0.0f, w = 0.0f;
        for (int r = 0; r < nRel; ++r) {
            float ex = __expf(att[f * nRel + r] - m);
            sum += ex;
            w   += ex * rel[r * D + d];
        }
        disen[f * D + d] = w / sum;
    }
}

__global__ void kg_scatter(const float* __restrict__ ent, const float* __restrict__ rel,
                           const int* __restrict__ eidx, const int* __restrict__ etype,
                           float* __restrict__ eagg, float* __restrict__ cnt, int nE) {
    int gid = blockIdx.x * blockDim.x + threadIdx.x;
    int e = gid >> 6;
    if (e >= nE) return;
    int d = gid & 63;
    int head = eidx[e];
    int tail = eidx[nE + e];
    int t = etype[e];
    float v = ent[tail * D + d] * rel[t * D + d];
    atomicAdd(&eagg[(size_t)head * D + d], v);
    if (d == 0) atomicAdd(&cnt[head], 1.0f);
}

__global__ void spmm_scatter(const float* __restrict__ ent, const float* __restrict__ vals,
                             const int* __restrict__ rows, const int* __restrict__ cols,
                             float* __restrict__ uagg, int nnz) {
    int gid = blockIdx.x * blockDim.x + threadIdx.x;
    int i = gid >> 6;
    if (i >= nnz) return;
    int d = gid & 63;
    float v = ent[cols[i] * D + d] * vals[i];
    atomicAdd(&uagg[(size_t)rows[i] * D + d], v);
}

__global__ void ent_norm(float* __restrict__ eagg, const float* __restrict__ cnt,
                         int total) {
    int gid = blockIdx.x * blockDim.x + threadIdx.x;
    if (gid >= total) return;
    float c = cnt[gid >> 6];
    eagg[gid] /= fmaxf(c, 1.0f);
}

__global__ void user_final(const float* __restrict__ uemb, const float* __restrict__ lat,
                           const float* __restrict__ disen, float* __restrict__ uagg,
                           int nU) {
    int gid = blockIdx.x * blockDim.x + threadIdx.x;
    int u = gid >> 6;
    if (u >= nU) return;
    int d = gid & 63;
    float e = uemb[(size_t)u * D + d];
    float s[4];
#pragma unroll
    for (int f = 0; f < 4; ++f) {
        float p = e * lat[f * D + d];
#pragma unroll
        for (int off = 32; off > 0; off >>= 1) p += __shfl_xor(p, off, 64);
        s[f] = p;
    }
    float m = fmaxf(fmaxf(s[0], s[1]), fmaxf(s[2], s[3]));
    float sum = 0.0f;
#pragma unroll
    for (int f = 0; f < 4; ++f) { s[f] = __expf(s[f] - m); sum += s[f]; }
    float inv = 1.0f / sum;
    float w = 0.0f;
#pragma unroll
    for (int f = 0; f < 4; ++f) w += (s[f] * inv) * disen[f * D + d];
    size_t o = (size_t)u * D + d;
    float base = uagg[o];
    uagg[o] = w * base + base;
}

// ===========================================================================
extern "C" void kernel_launch(void* const* d_in, const int* in_sizes, int n_in,
                              void* d_out, int out_size, void* d_ws, size_t ws_size,
                              hipStream_t stream) {
    const float* ent   = (const float*)d_in[0];
    const float* uemb  = (const float*)d_in[1];
    const float* lat   = (const float*)d_in[2];
    const float* rel   = (const float*)d_in[3];
    const float* att   = (const float*)d_in[4];
    const float* vals  = (const float*)d_in[5];
    const int*   eidx  = (const int*)d_in[6];
    const int*   etype = (const int*)d_in[7];
    const int*   irows = (const int*)d_in[8];
    const int*   icols = (const int*)d_in[9];

    int nEnt = in_sizes[0] / D;
    int nU   = in_sizes[1] / D;
    int nF   = in_sizes[2] / D;
    int nRel = in_sizes[3] / D;
    int nnz  = in_sizes[5];
    int nE   = in_sizes[6] / 2;

    float* eagg = (float*)d_out;
    float* uagg = (float*)d_out + (size_t)nEnt * D;

    int NB_e = (nEnt + RPB - 1) / RPB;
    int NB_u = (nU + RPB - 1) / RPB;
    int cap_e = (nE / (NB_e > 0 ? NB_e : 1)) * 5 / 2 + 64;
    int cap_u = (nnz / (NB_u > 0 ? NB_u : 1)) * 5 / 2 + 64;

    // ---- workspace carve (256B-aligned) ----
    char* base = (char*)d_ws;
    size_t off = 0;
    auto carve = [&](size_t bytes) -> void* {
        void* r = base + off;
        off = (off + bytes + 255) & ~(size_t)255;
        return r;
    };
    float*          disen    = (float*)carve((size_t)nF * D * 4);
    unsigned short* entb     = (unsigned short*)carve((size_t)nEnt * D * 2);
    int*            g_cnt_e  = (int*)carve((size_t)NB_e * 4);   // zero-span start
    int*            g_cnt_u  = (int*)carve((size_t)NB_u * 4);
    int*            ovflag   = (int*)carve(2 * 4);
    int*            ovcnt_e  = (int*)carve((size_t)nEnt * 4);   // zero-span end
    int2*           rs_e     = (int2*)carve((size_t)nEnt * 8);
    int2*           rs_u     = (int2*)carve((size_t)nU * 8);
    int*            region_e = (int*)carve((size_t)NB_e * cap_e * 4);
    int2*           region_u = (int2*)carve((size_t)NB_u * cap_u * 8);
    size_t need = off;

    bool fast = (ws_size >= need) && (nF == 4) && (nRel <= 32) &&
                (nEnt <= NB_MAX * RPB) && (nU <= NB_MAX * RPB) &&
                (nEnt <= (1 << 20)) && (cap_e <= LCAP_E) && (cap_u <= LCAP_U) &&
                (nE > 0) && (nnz > 0);

    if (fast) {
        hipMemsetAsync(d_out, 0, (size_t)out_size * sizeof(float), stream);  // overflow base
        size_t zspan = (size_t)((char*)rs_e - (char*)g_cnt_e);
        hipMemsetAsync(g_cnt_e, 0, zspan, stream);

        {
            int total4 = nEnt * D / 4;
            int nconv = (total4 + 255) / 256;
            prep<<<nconv + 1, 256, 0, stream>>>((const float4*)ent, (ushort4*)entb,
                                                total4, att, rel, disen, nF, nRel, nconv);
        }

        int nbe = (nE + CHUNK - 1) / CHUNK;
        int nbu = (nnz + CHUNK - 1) / CHUNK;
        size_t part_lds = (size_t)5 * NB_MAX * 4 + (size_t)CHUNK * 8 + (size_t)CHUNK * 2;
        part_both<<<nbe + nbu, 256, part_lds, stream>>>(
            eidx, etype, nE, nbe, irows, icols, vals, nnz,
            g_cnt_e, region_e, cap_e, g_cnt_u, region_u, cap_u,
            ent, rel, eagg, uagg, ovcnt_e, ovflag);

        size_t sort_lds = (size_t)3 * RPB * 4 +
                          ((size_t)LCAP_U * 8 > (size_t)LCAP_E * 4 ?
                           (size_t)LCAP_U * 8 : (size_t)LCAP_E * 4);
        sort_both<<<NB_e + NB_u, 256, sort_lds, stream>>>(
            region_e, g_cnt_e, cap_e, rs_e, nEnt, NB_e,
            region_u, g_cnt_u, cap_u, rs_u, nU);

        long long rows = (long long)nEnt + nU;
        long long tot = rows * 64;
        agg_csr<<<(int)((tot + 255) / 256), 256, 0, stream>>>(
            entb, rel, region_e, rs_e, ovcnt_e, region_u, rs_u, ovflag,
            uemb, lat, disen, eagg, uagg, nEnt, nU);
        return;
    }

    // ---- fallback: direct atomics (round-3 proven path) ----
    {
        float* cnt = (float*)d_ws;
        size_t cnt_bytes = (((size_t)nEnt * sizeof(float)) + 255) & ~(size_t)255;
        float* disen3 = (float*)((char*)d_ws + cnt_bytes);

        hipMemsetAsync(d_out, 0, (size_t)out_size * sizeof(float), stream);
        hipMemsetAsync(cnt, 0, (size_t)nEnt * sizeof(float), stream);

        disen_kernel<<<1, 64, 0, stream>>>(att, rel, disen3, nF, nRel);
        {
            long long total = (long long)nE * 64;
            kg_scatter<<<(int)((total + 255) / 256), 256, 0, stream>>>(
                ent, rel, eidx, etype, eagg, cnt, nE);
        }
        {
            long long total = (long long)nnz * 64;
            spmm_scatter<<<(int)((total + 255) / 256), 256, 0, stream>>>(
                ent, vals, irows, icols, uagg, nnz);
        }
        {
            int total = nEnt * D;
            ent_norm<<<(total + 255) / 256, 256, 0, stream>>>(eagg, cnt, total);
        }
        {
            long long total = (long long)nU * 64;
            user_final<<<(int)((total + 255) / 256), 256, 0, stream>>>(
                uemb, lat, disen3, uagg, nU);
        }
    }
}